// Round 1
// 3608.733 us; speedup vs baseline: 1.1583x; 1.1583x over previous
//
#include <hip/hip_runtime.h>
#include <math.h>

#define BB   128
#define PP   256
#define PIX_ 256
#define DD   512
#define CC   10
#define MTOT (BB*PP)   // 32768
#define NK   1024      // packed complex N for the ff GEMM
#define KA   2048      // A2 / X / Y row length (hi|lo)
#define KB   3072      // Bt3 row length (hi|hi|lo)
#define NSLOT (MTOT/4) // 8192 partial slots (one per norm block, whole batch)

static constexpr float SCALE_F = 0.35355339059327373f; // 8/sqrt(512)
static constexpr float PI_F    = 3.14159265358979323846f;

typedef short bf16x8 __attribute__((ext_vector_type(8)));
typedef float f32x4  __attribute__((ext_vector_type(4)));

__device__ __forceinline__ unsigned short f2bf(float f) {
    union { float f; unsigned u; } v; v.f = f;
    unsigned r = v.u + 0x7FFF + ((v.u >> 16) & 1);   // RNE
    return (unsigned short)(r >> 16);
}
__device__ __forceinline__ float bf2f(unsigned short h) {
    union { unsigned u; float f; } v; v.u = ((unsigned)h) << 16;
    return v.f;
}

// async global->LDS, 16B per lane; LDS dest = wave-uniform base + lane*16B (m97 pattern)
typedef __attribute__((address_space(3))) unsigned lds_u32;
typedef __attribute__((address_space(1))) const unsigned glb_u32;
__device__ __forceinline__ void gl2lds16(const unsigned short* g, short* l) {
    __builtin_amdgcn_global_load_lds((glb_u32*)g, (lds_u32*)l, 16, 0, 0);
}

// ---------------- setup ----------------
__global__ void k_setup(const float* __restrict__ q_rot, const float* __restrict__ k_rot,
                        const float* __restrict__ v_rot,
                        float* __restrict__ freq, float* __restrict__ cd, float* __restrict__ sd,
                        float* __restrict__ cv, float* __restrict__ sv,
                        int* __restrict__ active) {
    int t = threadIdx.x;
    if (t < DD) {
        freq[t] = expf(-(float)t * (9.210340371976184f / 512.0f)); // 10000^(-d/512)
        float dl = q_rot[t] - k_rot[t];
        cd[t] = cosf(dl);       sd[t] = sinf(dl);
        cv[t] = cosf(v_rot[t]); sv[t] = sinf(v_rot[t]);
    }
    if (t == 0) *active = 1;
}

// ---------------- build Bt3[n][0:3072] = [Bhi | Bhi | Blo] (k-major) ----------------
__global__ __launch_bounds__(256) void k_prep3(const float* __restrict__ Fr, const float* __restrict__ Fi,
                                               unsigned short* __restrict__ Bt3) {
    const int n = blockIdx.x;           // 0..1023
    const int t = threadIdx.x;
    unsigned short* row = Bt3 + (size_t)n * KB;
#pragma unroll
    for (int j4 = 0; j4 < 4; j4++) {
        const int j = j4 * 256 + t;
        float v;
        if (n < 512) v = (j < 512) ? Fr[(size_t)j * DD + n] : -Fi[(size_t)(j - 512) * DD + n];
        else         v = (j < 512) ? Fi[(size_t)j * DD + (n - 512)] : Fr[(size_t)(j - 512) * DD + (n - 512)];
        const unsigned short hi = f2bf(v);
        const unsigned short lo = f2bf(v - bf2f(hi));
        row[j] = hi; row[NK + j] = hi; row[2 * NK + j] = lo;
    }
}

#define SCAT4(TILE, V4) do { TILE[lk+0][lrow]=(V4).x; TILE[lk+1][lrow]=(V4).y; \
                             TILE[lk+2][lrow]=(V4).z; TILE[lk+3][lrow]=(V4).w; } while(0)

// ---------------- init: state = tanh(x@Wp^T + bp) * e^{i*p*freq*pi} ---------------- (R2-proven)
__global__ __launch_bounds__(256) void k_init(const float* __restrict__ x,
        const float* __restrict__ Wp, const float* __restrict__ bp,
        const float* __restrict__ freq,
        float* __restrict__ Sr, float* __restrict__ Si) {
    __shared__ float As[16][68];
    __shared__ float Bs[16][68];
    const int bm = blockIdx.y * 64, bn = blockIdx.x * 64;
    const int t = threadIdx.x, tx = t & 15, ty = t >> 4;
    const int lrow = t >> 2, lk = (t & 3) * 4;
    float acc[4][4] = {};
    for (int k0 = 0; k0 < PIX_; k0 += 16) {
        const float4 a4 = *(const float4*)(x  + (size_t)(bm + lrow) * PIX_ + k0 + lk);
        const float4 b4 = *(const float4*)(Wp + (size_t)(bn + lrow) * PIX_ + k0 + lk);
        __syncthreads();
        SCAT4(As, a4);
        SCAT4(Bs, b4);
        __syncthreads();
#pragma unroll
        for (int kk = 0; kk < 16; ++kk) {
            const float4 av = *(const float4*)&As[kk][ty * 4];
            const float4 bv = *(const float4*)&Bs[kk][tx * 4];
            const float a[4] = {av.x, av.y, av.z, av.w};
            const float b[4] = {bv.x, bv.y, bv.z, bv.w};
#pragma unroll
            for (int i = 0; i < 4; i++)
#pragma unroll
                for (int j = 0; j < 4; j++) acc[i][j] = fmaf(a[i], b[j], acc[i][j]);
        }
    }
#pragma unroll
    for (int i = 0; i < 4; i++) {
        const int m = bm + ty * 4 + i;
        const int p = m & 255;
        float4 vr, vi;
        float* pvr = (float*)&vr; float* pvi = (float*)&vi;
#pragma unroll
        for (int j = 0; j < 4; j++) {
            const int d = bn + tx * 4 + j;
            const float mg = tanhf(acc[i][j] + bp[d]);
            const float ph = (float)p * freq[d] * PI_F;
            float sph, cph; sincosf(ph, &sph, &cph);
            pvr[j] = mg * cph; pvi[j] = mg * sph;
        }
        *(float4*)(Sr + (size_t)m * DD + bn + tx * 4) = vr;
        *(float4*)(Si + (size_t)m * DD + bn + tx * 4) = vi;
    }
}

// ---------------- X/Y pack: X=[hi(sr|si)|lo], Y=[hi(krot)|lo] per chunk-row ---------------- (R12-proven)
__global__ __launch_bounds__(256) void k_xy(const float* __restrict__ Sr, const float* __restrict__ Si,
        const float* __restrict__ cd, const float* __restrict__ sd,
        unsigned short* __restrict__ X, unsigned short* __restrict__ Y,
        const int* __restrict__ active) {
    if (*active == 0) return;
    const int r = blockIdx.x, t = threadIdx.x;
    const size_t base = (size_t)r * DD + 2 * t;
    const float2 s_r = *(const float2*)(Sr + base);
    const float2 s_i = *(const float2*)(Si + base);
    const float2 c2  = *(const float2*)(cd + 2 * t);
    const float2 s2  = *(const float2*)(sd + 2 * t);
    unsigned short* xr = X + (size_t)r * KA;
    unsigned short* yr = Y + (size_t)r * KA;
    const float srv[2] = {s_r.x, s_r.y}, siv[2] = {s_i.x, s_i.y};
    const float cv_[2] = {c2.x, c2.y},  sv_[2] = {s2.x, s2.y};
    ushort2 xh_r, xh_i, xl_r, xl_i, yh_r, yh_i, yl_r, yl_i;
    unsigned short* o[8] = {(unsigned short*)&xh_r, (unsigned short*)&xh_i,
                            (unsigned short*)&xl_r, (unsigned short*)&xl_i,
                            (unsigned short*)&yh_r, (unsigned short*)&yh_i,
                            (unsigned short*)&yl_r, (unsigned short*)&yl_i};
#pragma unroll
    for (int e = 0; e < 2; e++) {
        const unsigned short hr = f2bf(srv[e]);
        const unsigned short hi_ = f2bf(siv[e]);
        o[0][e] = hr;  o[2][e] = f2bf(srv[e] - bf2f(hr));
        o[1][e] = hi_; o[3][e] = f2bf(siv[e] - bf2f(hi_));
        const float krr = srv[e] * cv_[e] + siv[e] * sv_[e];
        const float kri = siv[e] * cv_[e] - srv[e] * sv_[e];
        const unsigned short yh1 = f2bf(krr);
        const unsigned short yh2 = f2bf(kri);
        o[4][e] = yh1; o[6][e] = f2bf(krr - bf2f(yh1));
        o[5][e] = yh2; o[7][e] = f2bf(kri - bf2f(yh2));
    }
    *(ushort2*)(xr + 2 * t)        = xh_r;
    *(ushort2*)(xr + 512 + 2 * t)  = xh_i;
    *(ushort2*)(xr + 1024 + 2 * t) = xl_r;
    *(ushort2*)(xr + 1536 + 2 * t) = xl_i;
    *(ushort2*)(yr + 2 * t)        = yh_r;
    *(ushort2*)(yr + 512 + 2 * t)  = yh_i;
    *(ushort2*)(yr + 1024 + 2 * t) = yl_r;
    *(ushort2*)(yr + 1536 + 2 * t) = yl_i;
}

// ---------------- scores via split-bf16 MFMA: S = scale*(X @ Y^T), 3-term K=3072 ---------------- (R12-proven)
__global__ __launch_bounds__(256) void k_score_mfma(const unsigned short* __restrict__ X,
        const unsigned short* __restrict__ Y,
        float* __restrict__ Asc, const int* __restrict__ active) {
    if (*active == 0) return;
    __shared__ short Al[128][32];
    __shared__ short Bl[128][32];
    const int t = threadIdx.x;
    const int w = t >> 6, L = t & 63;
    const int lane15 = L & 15, quad = L >> 4;
    const int bm = blockIdx.y * 128;
    const int bnG = (((int)blockIdx.y >> 1) * 2 + (int)blockIdx.x) * 128; // Y rows, same sample
    const int qb = blockIdx.x * 128;                                     // q-col base in sample
    const int gr = t >> 2, ch = (t & 3) * 8;
    short* AlW0 = &Al[0][0] + w * 512;
    short* AlW1 = AlW0 + 64 * 32;
    short* BlW0 = &Bl[0][0] + w * 512;
    short* BlW1 = BlW0 + 64 * 32;
    f32x4 acc[2][8] = {};
    for (int k0 = 0; k0 < KB; k0 += 32) {
        const int acol = (k0 < 2048) ? k0 : (k0 - 2048);
        const int bcol = (k0 < 1024) ? k0 : (k0 - 1024);
        __syncthreads();
        gl2lds16(X + (size_t)(bm + gr) * KA      + acol + ch, AlW0);
        gl2lds16(X + (size_t)(bm + 64 + gr) * KA + acol + ch, AlW1);
        gl2lds16(Y + (size_t)(bnG + gr) * KA      + bcol + ch, BlW0);
        gl2lds16(Y + (size_t)(bnG + 64 + gr) * KA + bcol + ch, BlW1);
        __syncthreads();
        bf16x8 bf[8];
#pragma unroll
        for (int tc = 0; tc < 8; tc++)
            bf[tc] = *(const bf16x8*)&Bl[tc * 16 + lane15][quad * 8];
#pragma unroll
        for (int tr = 0; tr < 2; tr++) {
            const bf16x8 af = *(const bf16x8*)&Al[w * 32 + tr * 16 + lane15][quad * 8];
#pragma unroll
            for (int tc = 0; tc < 8; tc++)
                acc[tr][tc] = __builtin_amdgcn_mfma_f32_16x16x32_bf16(af, bf[tc], acc[tr][tc], 0, 0, 0);
        }
    }
#pragma unroll
    for (int tr = 0; tr < 2; tr++)
#pragma unroll
        for (int tc = 0; tc < 8; tc++) {
            const int q = qb + tc * 16 + lane15;
            const int mbase = bm + w * 32 + tr * 16 + quad * 4;
#pragma unroll
            for (int r = 0; r < 4; r++)
                Asc[(size_t)(mbase + r) * PP + q] = acc[tr][tc][r] * SCALE_F;
        }
}

// ---------------- softmax over rows of length 256, one wave per row ----------------
// R(new): writes split-bf16 attn rows [Ah(256)|Al(256)] for the MFMA attnout; drops fp32 write-back
__global__ __launch_bounds__(256) void k_softmax(const float* __restrict__ A,
        unsigned short* __restrict__ Asp, const int* __restrict__ active) {
    if (*active == 0) return;
    const int row = blockIdx.x * 4 + (threadIdx.x >> 6);
    const int lane = threadIdx.x & 63;
    const float* a = A + (size_t)row * PP;
    unsigned short* o = Asp + (size_t)row * 512;
    float v[4];
#pragma unroll
    for (int k = 0; k < 4; k++) v[k] = a[lane + 64 * k];
    float m = fmaxf(fmaxf(v[0], v[1]), fmaxf(v[2], v[3]));
#pragma unroll
    for (int off = 32; off; off >>= 1) m = fmaxf(m, __shfl_xor(m, off, 64));
    float s = 0.f;
#pragma unroll
    for (int k = 0; k < 4; k++) { v[k] = __expf(v[k] - m); s += v[k]; }
#pragma unroll
    for (int off = 32; off; off >>= 1) s += __shfl_xor(s, off, 64);
    const float inv = 1.0f / s;
#pragma unroll
    for (int k = 0; k < 4; k++) {
        const float val = v[k] * inv;
        const unsigned short h = f2bf(val);
        o[lane + 64 * k] = h;
        o[256 + lane + 64 * k] = f2bf(val - bf2f(h));
    }
}

// ---------------- attn_out via split-bf16 MFMA (3-term), fused v-rot + prev-add epilogue ----------------
// Out[p, n<512]=Sum_q A[p,q]*Sr[q,n]; n>=512 -> Si. B operand (S^T, hi/lo) reg-staged from X
// (X already holds the exact hi/lo split of the state). Block: M=128 rows x N=64 d (real tc0-3 +
// imag tc4-7 of the SAME d-range -> wr/wi in the same lane for the rotation epilogue).
__global__ __launch_bounds__(256) void k_attnout_mfma(const unsigned short* __restrict__ Asp,
        const unsigned short* __restrict__ X,
        const float* __restrict__ Sr, const float* __restrict__ Si,
        const float* __restrict__ cv, const float* __restrict__ sv,
        unsigned short* __restrict__ A2, const int* __restrict__ active) {
    if (*active == 0) return;
    __shared__ short AhT[128][32];
    __shared__ short AlT[128][32];
    __shared__ short BH[128][40];   // +8 pad: 80B row stride -> b128 r/w at the bank floor
    __shared__ short BL[128][40];
    const int t = threadIdx.x;
    const int w = t >> 6, L = t & 63;
    const int lane15 = L & 15, quad = L >> 4;
    const int bm = blockIdx.y * 128;          // chunk-local row base
    const int bn = blockIdx.x * 64;           // d base (0..448)
    const int sample = blockIdx.y >> 1;       // chunk-local sample
    const int gr = t >> 2, ch = (t & 3) * 8;
    short* AhW0 = &AhT[0][0] + w * 512;
    short* AhW1 = AhW0 + 64 * 32;
    short* AlW0 = &AlT[0][0] + w * 512;
    short* AlW1 = AlW0 + 64 * 32;
    // B staging: thread owns one n' (0..127) and 16 q's (kh*16..+15)
    const int nn = t & 127, kh = t >> 7;
    const unsigned short* Bsrc = X + (size_t)sample * PP * KA
                               + ((nn < 64) ? (bn + nn) : (512 + bn + nn - 64));
    f32x4 acc[2][8] = {};
    for (int q0 = 0; q0 < PP; q0 += 32) {
        __syncthreads();
        gl2lds16(Asp + (size_t)(bm + gr) * 512      + q0 + ch,       AhW0);
        gl2lds16(Asp + (size_t)(bm + 64 + gr) * 512 + q0 + ch,       AhW1);
        gl2lds16(Asp + (size_t)(bm + gr) * 512      + 256 + q0 + ch, AlW0);
        gl2lds16(Asp + (size_t)(bm + 64 + gr) * 512 + 256 + q0 + ch, AlW1);
#pragma unroll
        for (int kg = 0; kg < 2; kg++) {
            const int qb = kh * 16 + kg * 8;
            bf16x8 hh, ll;
#pragma unroll
            for (int j = 0; j < 8; j++) {
                const size_t o = (size_t)(q0 + qb + j) * KA;
                hh[j] = (short)Bsrc[o];
                ll[j] = (short)Bsrc[o + 1024];
            }
            *(bf16x8*)&BH[nn][qb] = hh;
            *(bf16x8*)&BL[nn][qb] = ll;
        }
        __syncthreads();
        bf16x8 bh[8];
#pragma unroll
        for (int tc = 0; tc < 8; tc++)
            bh[tc] = *(const bf16x8*)&BH[tc * 16 + lane15][quad * 8];
        bf16x8 afh[2];
#pragma unroll
        for (int tr = 0; tr < 2; tr++) {
            afh[tr] = *(const bf16x8*)&AhT[w * 32 + tr * 16 + lane15][quad * 8];
            const bf16x8 afl = *(const bf16x8*)&AlT[w * 32 + tr * 16 + lane15][quad * 8];
#pragma unroll
            for (int tc = 0; tc < 8; tc++)
                acc[tr][tc] = __builtin_amdgcn_mfma_f32_16x16x32_bf16(afh[tr], bh[tc], acc[tr][tc], 0, 0, 0);
#pragma unroll
            for (int tc = 0; tc < 8; tc++)
                acc[tr][tc] = __builtin_amdgcn_mfma_f32_16x16x32_bf16(afl, bh[tc], acc[tr][tc], 0, 0, 0);
        }
#pragma unroll
        for (int tc = 0; tc < 8; tc++) {
            const bf16x8 bl = *(const bf16x8*)&BL[tc * 16 + lane15][quad * 8];
            acc[0][tc] = __builtin_amdgcn_mfma_f32_16x16x32_bf16(afh[0], bl, acc[0][tc], 0, 0, 0);
            acc[1][tc] = __builtin_amdgcn_mfma_f32_16x16x32_bf16(afh[1], bl, acc[1][tc], 0, 0, 0);
        }
    }
    // epilogue: tr_ = prev_r + wr*cv - wi*sv; ti_ = prev_i + wr*sv + wi*cv; split -> A2
#pragma unroll
    for (int tr = 0; tr < 2; tr++) {
#pragma unroll
        for (int tc = 0; tc < 4; tc++) {
            const int d = bn + tc * 16 + lane15;
            const float cvd = cv[d], svd = sv[d];
#pragma unroll
            for (int r = 0; r < 4; r++) {
                const int m = bm + w * 32 + tr * 16 + quad * 4 + r;  // chunk-local row
                const float wr = acc[tr][tc][r];
                const float wi = acc[tr][tc + 4][r];
                const float tr_ = Sr[(size_t)m * DD + d] + (wr * cvd - wi * svd);
                const float ti_ = Si[(size_t)m * DD + d] + (wr * svd + wi * cvd);
                const unsigned short rh = f2bf(tr_);
                const unsigned short ih = f2bf(ti_);
                unsigned short* arow = A2 + (size_t)m * KA;
                arow[d]        = rh;
                arow[512 + d]  = ih;
                arow[1024 + d] = f2bf(tr_ - bf2f(rh));
                arow[1536 + d] = f2bf(ti_ - bf2f(ih));
            }
        }
    }
}

// ---------------- ff via split-bf16 MFMA, global_load_lds staging ---------------- (R9-proven)
__global__ __launch_bounds__(256) void k_ff_mfma3(const unsigned short* __restrict__ A2,
        const unsigned short* __restrict__ Bt3,
        float* __restrict__ U, const int* __restrict__ active) {
    if (*active == 0) return;
    __shared__ short Al[128][32];
    __shared__ short Bl[128][32];
    const int t = threadIdx.x;
    const int w = t >> 6, L = t & 63;
    const int lane15 = L & 15, quad = L >> 4;
    const int bm = blockIdx.y * 128, bn = blockIdx.x * 128;
    const int gr = t >> 2, ch = (t & 3) * 8;
    short* AlW0 = &Al[0][0] + w * 512;
    short* AlW1 = AlW0 + 64 * 32;
    short* BlW0 = &Bl[0][0] + w * 512;
    short* BlW1 = BlW0 + 64 * 32;
    f32x4 acc[2][8] = {};
    for (int k0 = 0; k0 < KB; k0 += 32) {
        const int acol = (k0 < 2048) ? k0 : (k0 - 2048);
        __syncthreads();
        gl2lds16(A2  + (size_t)(bm + gr) * KA      + acol + ch, AlW0);
        gl2lds16(A2  + (size_t)(bm + 64 + gr) * KA + acol + ch, AlW1);
        gl2lds16(Bt3 + (size_t)(bn + gr) * KB      + k0 + ch,   BlW0);
        gl2lds16(Bt3 + (size_t)(bn + 64 + gr) * KB + k0 + ch,   BlW1);
        __syncthreads();
        bf16x8 bf[8];
#pragma unroll
        for (int tc = 0; tc < 8; tc++)
            bf[tc] = *(const bf16x8*)&Bl[tc * 16 + lane15][quad * 8];
#pragma unroll
        for (int tr = 0; tr < 2; tr++) {
            const bf16x8 af = *(const bf16x8*)&Al[w * 32 + tr * 16 + lane15][quad * 8];
#pragma unroll
            for (int tc = 0; tc < 8; tc++)
                acc[tr][tc] = __builtin_amdgcn_mfma_f32_16x16x32_bf16(af, bf[tc], acc[tr][tc], 0, 0, 0);
        }
    }
#pragma unroll
    for (int tr = 0; tr < 2; tr++)
#pragma unroll
        for (int tc = 0; tc < 8; tc++) {
            const int n = bn + tc * 16 + lane15;
            const int mbase = bm + w * 32 + tr * 16 + quad * 4;
#pragma unroll
            for (int r = 0; r < 4; r++)
                U[(size_t)(mbase + r) * NK + n] = acc[tr][tc][r];
        }
}

// ---------------- complex_norm + commit + per-block partial (NO atomics) ---------------- (R8-proven)
__global__ __launch_bounds__(256) void k_norm(const float* __restrict__ U,
        float* __restrict__ Sr, float* __restrict__ Si,
        float* __restrict__ part, const int* __restrict__ active) {
    if (*active == 0) return;
    __shared__ float red[8];
    const int t = threadIdx.x, rt = t >> 6, L = t & 63;
    const int row = blockIdx.x * 4 + rt;
    const size_t ub = (size_t)row * NK;
    const size_t base = (size_t)row * DD;
    const float4 ur0 = *(const float4*)(U + ub + 4 * L);
    const float4 ur1 = *(const float4*)(U + ub + 256 + 4 * L);
    const float4 ui0 = *(const float4*)(U + ub + 512 + 4 * L);
    const float4 ui1 = *(const float4*)(U + ub + 768 + 4 * L);
    const float4 pr0 = *(const float4*)(Sr + base + 4 * L);
    const float4 pr1 = *(const float4*)(Sr + base + 256 + 4 * L);
    const float4 pi0 = *(const float4*)(Si + base + 4 * L);
    const float4 pi1 = *(const float4*)(Si + base + 256 + 4 * L);
    const float urr[8] = {ur0.x, ur0.y, ur0.z, ur0.w, ur1.x, ur1.y, ur1.z, ur1.w};
    const float uii[8] = {ui0.x, ui0.y, ui0.z, ui0.w, ui1.x, ui1.y, ui1.z, ui1.w};
    float mg[8], msum = 0.f;
#pragma unroll
    for (int e = 0; e < 8; e++) {
        mg[e] = sqrtf(urr[e] * urr[e] + uii[e] * uii[e]);
        msum += mg[e];
    }
#pragma unroll
    for (int off = 32; off; off >>= 1) msum += __shfl_xor(msum, off, 64);
    const float mean = msum * (1.0f / 512.0f);
    float vs = 0.f;
#pragma unroll
    for (int e = 0; e < 8; e++) { const float d = mg[e] - mean; vs += d * d; }
#pragma unroll
    for (int off = 32; off; off >>= 1) vs += __shfl_xor(vs, off, 64);
    const float istd = 1.0f / (sqrtf(vs * (1.0f / 511.0f)) + 1e-5f);
    float nr[8], ni[8];
#pragma unroll
    for (int e = 0; e < 8; e++) {
        const float sc = tanhf((mg[e] - mean) * istd) / (mg[e] + 1e-5f);
        nr[e] = urr[e] * sc; ni[e] = uii[e] * sc;
    }
    const float prr[8] = {pr0.x, pr0.y, pr0.z, pr0.w, pr1.x, pr1.y, pr1.z, pr1.w};
    const float pii[8] = {pi0.x, pi0.y, pi0.z, pi0.w, pi1.x, pi1.y, pi1.z, pi1.w};
    float dd = 0.f, nn = 0.f;
#pragma unroll
    for (int e = 0; e < 8; e++) {
        const float dr = nr[e] - prr[e], di = ni[e] - pii[e];
        dd += dr * dr + di * di;
        nn += nr[e] * nr[e] + ni[e] * ni[e];
    }
    *(float4*)(Sr + base + 4 * L)       = make_float4(nr[0], nr[1], nr[2], nr[3]);
    *(float4*)(Sr + base + 256 + 4 * L) = make_float4(nr[4], nr[5], nr[6], nr[7]);
    *(float4*)(Si + base + 4 * L)       = make_float4(ni[0], ni[1], ni[2], ni[3]);
    *(float4*)(Si + base + 256 + 4 * L) = make_float4(ni[4], ni[5], ni[6], ni[7]);
#pragma unroll
    for (int off = 32; off; off >>= 1) {
        dd += __shfl_xor(dd, off, 64);
        nn += __shfl_xor(nn, off, 64);
    }
    if (L == 0) { red[rt] = dd; red[4 + rt] = nn; }
    __syncthreads();
    if (t == 0)
        *(float2*)(part + 2 * blockIdx.x) =
            make_float2(red[0] + red[1] + red[2] + red[3],
                        red[4] + red[5] + red[6] + red[7]);
}

// ---------------- convergence flag: reduce all NSLOT partials ----------------
__global__ __launch_bounds__(256) void k_flag(const float* __restrict__ part, int* __restrict__ active) {
    __shared__ float red[8];
    const int t = threadIdx.x, rt = t >> 6, L = t & 63;
    float dd = 0.f, nn = 0.f;
    for (int i = t; i < NSLOT; i += 256) {
        const float2 p = *(const float2*)(part + 2 * i);
        dd += p.x; nn += p.y;
    }
#pragma unroll
    for (int off = 32; off; off >>= 1) {
        dd += __shfl_xor(dd, off, 64);
        nn += __shfl_xor(nn, off, 64);
    }
    if (L == 0) { red[rt] = dd; red[4 + rt] = nn; }
    __syncthreads();
    if (t == 0) {
        const float d = red[0] + red[1] + red[2] + red[3];
        const float n = red[4] + red[5] + red[6] + red[7];
        const float diff = sqrtf(d) / (sqrtf(n) + 1e-8f);
        const int a = *active;
        *active = (a && (diff >= 1e-3f)) ? 1 : 0;
    }
}

// ---------------- mean over P ----------------
__global__ __launch_bounds__(256) void k_pool(const float* __restrict__ Sr, const float* __restrict__ Si,
        float* __restrict__ Pr, float* __restrict__ Pi) {
    const int gid = blockIdx.x * 256 + threadIdx.x;
    const int b = gid >> 9, d = gid & 511;
    const size_t base = (size_t)b * PP * DD + d;
    float sr = 0.f, si = 0.f;
    for (int p = 0; p < PP; p++) {
        sr += Sr[base + (size_t)p * DD];
        si += Si[base + (size_t)p * DD];
    }
    Pr[gid] = sr * (1.0f / 256.0f);
    Pi[gid] = si * (1.0f / 256.0f);
}

// ---------------- logits ----------------
__global__ __launch_bounds__(64) void k_logits(const float* __restrict__ Pr, const float* __restrict__ Pi,
        const float* __restrict__ Wr, const float* __restrict__ br,
        const float* __restrict__ Wi, const float* __restrict__ bi,
        float* __restrict__ out) {
    const int b = blockIdx.x;
    const int lane = threadIdx.x;
    for (int c = 0; c < CC; c++) {
        float acc = 0.f;
#pragma unroll
        for (int k = 0; k < 8; k++) {
            const int d = lane + 64 * k;
            acc += Pr[b * DD + d] * Wr[c * DD + d] + Pi[b * DD + d] * Wi[c * DD + d];
        }
#pragma unroll
        for (int off = 32; off; off >>= 1) acc += __shfl_xor(acc, off, 64);
        if (lane == 0) out[b * CC + c] = acc + br[c] + bi[c];
    }
}

extern "C" void kernel_launch(void* const* d_in, const int* in_sizes, int n_in,
                              void* d_out, int out_size, void* d_ws, size_t ws_size,
                              hipStream_t stream) {
    const float* x     = (const float*)d_in[0];
    const float* Wp    = (const float*)d_in[1];
    const float* bp    = (const float*)d_in[2];
    const float* q_rot = (const float*)d_in[3];
    const float* k_rot = (const float*)d_in[4];
    const float* v_rot = (const float*)d_in[5];
    const float* ffr   = (const float*)d_in[6];
    const float* ffi   = (const float*)d_in[7];
    const float* Wr    = (const float*)d_in[8];
    const float* br    = (const float*)d_in[9];
    const float* Wi    = (const float*)d_in[10];
    const float* bi    = (const float*)d_in[11];
    float* out = (float*)d_out;

    float* ws = (float*)d_ws;
    const size_t plane = (size_t)MTOT * DD;      // 16,777,216 floats
    const size_t sline = (size_t)PP * DD;

    float* freq = ws;                  // 512
    float* cd   = freq + DD;
    float* sd   = cd + DD;
    float* cv   = sd + DD;
    float* sv   = cv + DD;
    int*   active = (int*)(sv + DD);   // 1
    float* Pr = ws + 4096;             // 65536
    float* Pi = Pr + (size_t)BB * DD;  // 65536
    float* part = Pi + (size_t)BB * DD;        // 2*NSLOT = 16384 floats
    float* Sr = part + 2 * NSLOT;              // fp32 state (128 MiB)
    float* Si = Sr + plane;
    unsigned short* Bt3 = (unsigned short*)(Si + plane);  // 1024x3072 bf16 (6 MB)
    float* chunkbase = Si + plane + (size_t)NK * KB / 2;

    const size_t fixed_f = (4096 + 2 * (size_t)BB * DD + 2 * NSLOT) + 2 * plane + (size_t)NK * KB / 2;
    // per-sample: U (PP*NK f32) + X (PP*KA bf16) + Y/A2 overlay (PP*KA bf16) = 786432 floats = 3 MB
    const size_t perC_f = (size_t)PP * NK + (size_t)PP * KA;   // 786432

    // R9-proven power-of-2 chunking.
    int C = BB;
    while (C > 1 && (fixed_f + (size_t)C * perC_f) * 4ull > ws_size) C >>= 1;

    float* U = chunkbase;                                   // C x 256 x 1024 fp32
    float* Asc = U;                                         // overlay; dead before U written
    unsigned short* Asp = (unsigned short*)(U + (size_t)C * PP * PP);  // split attn, after Asc in U region
    unsigned short* X  = (unsigned short*)(U + (size_t)C * PP * NK);   // C x 256 x 2048 bf16 (state split)
    unsigned short* Y  = X + (size_t)C * PP * KA;           // C x 256 x 2048 bf16 (k-rot)
    unsigned short* A2 = Y;                                 // overlay: Y dead after k_score; X stays live

    k_setup<<<1, 512, 0, stream>>>(q_rot, k_rot, v_rot, freq, cd, sd, cv, sv, active);
    k_prep3<<<NK, 256, 0, stream>>>(ffr, ffi, Bt3);
    k_init<<<dim3(DD / 64, MTOT / 64), 256, 0, stream>>>(x, Wp, bp, freq, Sr, Si);

    for (int it = 0; it < 4; ++it) {
        for (int c0 = 0; c0 < BB; c0 += C) {
            float* Sr_c = Sr + (size_t)c0 * sline;
            float* Si_c = Si + (size_t)c0 * sline;
            float* part_c = part + (size_t)c0 * (PP / 4) * 2;
            k_xy<<<C * PP, 256, 0, stream>>>(Sr_c, Si_c, cd, sd, X, Y, active);
            k_score_mfma<<<dim3(2, C * 2), 256, 0, stream>>>(X, Y, Asc, active);
            k_softmax<<<C * PP / 4, 256, 0, stream>>>(Asc, Asp, active);
            k_attnout_mfma<<<dim3(8, C * 2), 256, 0, stream>>>(Asp, X, Sr_c, Si_c, cv, sv, A2, active);
            k_ff_mfma3<<<dim3(NK / 128, C * 2), 256, 0, stream>>>(A2, Bt3, U, active);
            k_norm<<<C * (PP / 4), 256, 0, stream>>>(U, Sr_c, Si_c, part_c, active);
        }
        k_flag<<<1, 256, 0, stream>>>(part, active);
    }

    k_pool<<<BB * DD / 256, 256, 0, stream>>>(Sr, Si, Pr, Pi);
    k_logits<<<BB, 64, 0, stream>>>(Pr, Pi, Wr, br, Wi, bi, out);
}

// Round 2
// 3267.836 us; speedup vs baseline: 1.2792x; 1.1043x over previous
//
#include <hip/hip_runtime.h>
#include <math.h>

#define BB   128
#define PP   256
#define PIX_ 256
#define DD   512
#define CC   10
#define MTOT (BB*PP)   // 32768
#define NK   1024      // packed complex N for the ff GEMM
#define KA   2048      // A2 / X / Y row length (hi|lo)
#define KB2  2048      // Bt2 row length (hi|lo)
#define NSLOT (MTOT/4) // 8192 partial slots (one per norm block, whole batch)

static constexpr float SCALE_F = 0.35355339059327373f; // 8/sqrt(512)
static constexpr float PI_F    = 3.14159265358979323846f;

typedef short bf16x8 __attribute__((ext_vector_type(8)));
typedef float f32x4  __attribute__((ext_vector_type(4)));

__device__ __forceinline__ unsigned short f2bf(float f) {
    union { float f; unsigned u; } v; v.f = f;
    unsigned r = v.u + 0x7FFF + ((v.u >> 16) & 1);   // RNE
    return (unsigned short)(r >> 16);
}
__device__ __forceinline__ float bf2f(unsigned short h) {
    union { unsigned u; float f; } v; v.u = ((unsigned)h) << 16;
    return v.f;
}

// async global->LDS, 16B per lane; LDS dest = wave-uniform base + lane*16B (m97 pattern)
typedef __attribute__((address_space(3))) unsigned lds_u32;
typedef __attribute__((address_space(1))) const unsigned glb_u32;
__device__ __forceinline__ void gl2lds16(const unsigned short* g, short* l) {
    __builtin_amdgcn_global_load_lds((glb_u32*)g, (lds_u32*)l, 16, 0, 0);
}

// ---------------- setup ----------------
__global__ void k_setup(const float* __restrict__ q_rot, const float* __restrict__ k_rot,
                        const float* __restrict__ v_rot,
                        float* __restrict__ freq, float* __restrict__ cd, float* __restrict__ sd,
                        float* __restrict__ cv, float* __restrict__ sv,
                        int* __restrict__ active) {
    int t = threadIdx.x;
    if (t < DD) {
        freq[t] = expf(-(float)t * (9.210340371976184f / 512.0f)); // 10000^(-d/512)
        float dl = q_rot[t] - k_rot[t];
        cd[t] = cosf(dl);       sd[t] = sinf(dl);
        cv[t] = cosf(v_rot[t]); sv[t] = sinf(v_rot[t]);
    }
    if (t == 0) *active = 1;
}

// ---------------- build Bt2[n][0:2048] = [Bhi | Blo] (k-major) ----------------
__global__ __launch_bounds__(256) void k_prep2(const float* __restrict__ Fr, const float* __restrict__ Fi,
                                               unsigned short* __restrict__ Bt2) {
    const int n = blockIdx.x;           // 0..1023
    const int t = threadIdx.x;
    unsigned short* row = Bt2 + (size_t)n * KB2;
#pragma unroll
    for (int j4 = 0; j4 < 4; j4++) {
        const int j = j4 * 256 + t;
        float v;
        if (n < 512) v = (j < 512) ? Fr[(size_t)j * DD + n] : -Fi[(size_t)(j - 512) * DD + n];
        else         v = (j < 512) ? Fi[(size_t)j * DD + (n - 512)] : Fr[(size_t)(j - 512) * DD + (n - 512)];
        const unsigned short hi = f2bf(v);
        row[j] = hi;
        row[NK + j] = f2bf(v - bf2f(hi));
    }
}

// ---------------- pack x rows -> [hi(256)|lo(256)] ----------------
__global__ __launch_bounds__(256) void k_packx(const float* __restrict__ x, unsigned short* __restrict__ Xp) {
    const int r = blockIdx.x, t = threadIdx.x;
    const float v = x[(size_t)r * PIX_ + t];
    const unsigned short h = f2bf(v);
    Xp[(size_t)r * 512 + t] = h;
    Xp[(size_t)r * 512 + 256 + t] = f2bf(v - bf2f(h));
}

// ---------------- pack Wp rows -> [hi(256)|lo(256)] ----------------
__global__ __launch_bounds__(256) void k_wpack(const float* __restrict__ Wp, unsigned short* __restrict__ Wt) {
    const int d = blockIdx.x, t = threadIdx.x;
    const float v = Wp[(size_t)d * PIX_ + t];
    const unsigned short h = f2bf(v);
    Wt[(size_t)d * 512 + t] = h;
    Wt[(size_t)d * 512 + 256 + t] = f2bf(v - bf2f(h));
}

#define SCAT4(TILE, V4) do { TILE[lk+0][lrow]=(V4).x; TILE[lk+1][lrow]=(V4).y; \
                             TILE[lk+2][lrow]=(V4).z; TILE[lk+3][lrow]=(V4).w; } while(0)

// ---------------- init (fp32 fallback, small-ws path) ---------------- (R2-proven)
__global__ __launch_bounds__(256) void k_init(const float* __restrict__ x,
        const float* __restrict__ Wp, const float* __restrict__ bp,
        const float* __restrict__ freq,
        float* __restrict__ Sr, float* __restrict__ Si) {
    __shared__ float As[16][68];
    __shared__ float Bs[16][68];
    const int bm = blockIdx.y * 64, bn = blockIdx.x * 64;
    const int t = threadIdx.x, tx = t & 15, ty = t >> 4;
    const int lrow = t >> 2, lk = (t & 3) * 4;
    float acc[4][4] = {};
    for (int k0 = 0; k0 < PIX_; k0 += 16) {
        const float4 a4 = *(const float4*)(x  + (size_t)(bm + lrow) * PIX_ + k0 + lk);
        const float4 b4 = *(const float4*)(Wp + (size_t)(bn + lrow) * PIX_ + k0 + lk);
        __syncthreads();
        SCAT4(As, a4);
        SCAT4(Bs, b4);
        __syncthreads();
#pragma unroll
        for (int kk = 0; kk < 16; ++kk) {
            const float4 av = *(const float4*)&As[kk][ty * 4];
            const float4 bv = *(const float4*)&Bs[kk][tx * 4];
            const float a[4] = {av.x, av.y, av.z, av.w};
            const float b[4] = {bv.x, bv.y, bv.z, bv.w};
#pragma unroll
            for (int i = 0; i < 4; i++)
#pragma unroll
                for (int j = 0; j < 4; j++) acc[i][j] = fmaf(a[i], b[j], acc[i][j]);
        }
    }
#pragma unroll
    for (int i = 0; i < 4; i++) {
        const int m = bm + ty * 4 + i;
        const int p = m & 255;
        float4 vr, vi;
        float* pvr = (float*)&vr; float* pvi = (float*)&vi;
#pragma unroll
        for (int j = 0; j < 4; j++) {
            const int d = bn + tx * 4 + j;
            const float mg = tanhf(acc[i][j] + bp[d]);
            const float ph = (float)p * freq[d] * PI_F;
            float sph, cph; sincosf(ph, &sph, &cph);
            pvr[j] = mg * cph; pvi[j] = mg * sph;
        }
        *(float4*)(Sr + (size_t)m * DD + bn + tx * 4) = vr;
        *(float4*)(Si + (size_t)m * DD + bn + tx * 4) = vi;
    }
}

// ---------------- init via split-bf16 MFMA (3-term K=256), tanh+phase epilogue ----------------
__global__ __launch_bounds__(256) void k_init_mfma(const unsigned short* __restrict__ Xp,
        const unsigned short* __restrict__ Wt, const float* __restrict__ bp,
        const float* __restrict__ freq,
        float* __restrict__ Sr, float* __restrict__ Si) {
    __shared__ short AH[128][32], AL[128][32];
    __shared__ short BH[128][32], BL[128][32];
    const int t = threadIdx.x, w = t >> 6, L = t & 63;
    const int lane15 = L & 15, quad = L >> 4;
    const int bm = blockIdx.y * 128, bn = blockIdx.x * 128;
    const int gr = t >> 2, ch = (t & 3) * 8;
    short* AHw = &AH[0][0] + w * 512;
    short* ALw = &AL[0][0] + w * 512;
    short* BHw = &BH[0][0] + w * 512;
    short* BLw = &BL[0][0] + w * 512;
    f32x4 acc[2][8] = {};
    for (int k0 = 0; k0 < 256; k0 += 32) {
        __syncthreads();
        gl2lds16(Xp + (size_t)(bm + gr) * 512      + k0 + ch,       AHw);
        gl2lds16(Xp + (size_t)(bm + 64 + gr) * 512 + k0 + ch,       AHw + 64 * 32);
        gl2lds16(Xp + (size_t)(bm + gr) * 512      + 256 + k0 + ch, ALw);
        gl2lds16(Xp + (size_t)(bm + 64 + gr) * 512 + 256 + k0 + ch, ALw + 64 * 32);
        gl2lds16(Wt + (size_t)(bn + gr) * 512      + k0 + ch,       BHw);
        gl2lds16(Wt + (size_t)(bn + 64 + gr) * 512 + k0 + ch,       BHw + 64 * 32);
        gl2lds16(Wt + (size_t)(bn + gr) * 512      + 256 + k0 + ch, BLw);
        gl2lds16(Wt + (size_t)(bn + 64 + gr) * 512 + 256 + k0 + ch, BLw + 64 * 32);
        __syncthreads();
        bf16x8 ah[2], al[2];
#pragma unroll
        for (int tr = 0; tr < 2; tr++) {
            ah[tr] = *(const bf16x8*)&AH[w * 32 + tr * 16 + lane15][quad * 8];
            al[tr] = *(const bf16x8*)&AL[w * 32 + tr * 16 + lane15][quad * 8];
        }
#pragma unroll
        for (int tc = 0; tc < 8; tc++) {
            const bf16x8 bh = *(const bf16x8*)&BH[tc * 16 + lane15][quad * 8];
            acc[0][tc] = __builtin_amdgcn_mfma_f32_16x16x32_bf16(ah[0], bh, acc[0][tc], 0, 0, 0);
            acc[1][tc] = __builtin_amdgcn_mfma_f32_16x16x32_bf16(ah[1], bh, acc[1][tc], 0, 0, 0);
            acc[0][tc] = __builtin_amdgcn_mfma_f32_16x16x32_bf16(al[0], bh, acc[0][tc], 0, 0, 0);
            acc[1][tc] = __builtin_amdgcn_mfma_f32_16x16x32_bf16(al[1], bh, acc[1][tc], 0, 0, 0);
            const bf16x8 bl = *(const bf16x8*)&BL[tc * 16 + lane15][quad * 8];
            acc[0][tc] = __builtin_amdgcn_mfma_f32_16x16x32_bf16(ah[0], bl, acc[0][tc], 0, 0, 0);
            acc[1][tc] = __builtin_amdgcn_mfma_f32_16x16x32_bf16(ah[1], bl, acc[1][tc], 0, 0, 0);
        }
    }
#pragma unroll
    for (int tr = 0; tr < 2; tr++)
#pragma unroll
        for (int tc = 0; tc < 8; tc++) {
            const int d = bn + tc * 16 + lane15;
            const float bpd = bp[d];
            const float fq = freq[d] * PI_F;
#pragma unroll
            for (int r = 0; r < 4; r++) {
                const int m = bm + w * 32 + tr * 16 + quad * 4 + r;
                const int p = m & 255;
                const float mg = tanhf(acc[tr][tc][r] + bpd);
                float sph, cph; sincosf((float)p * fq, &sph, &cph);
                Sr[(size_t)m * DD + d] = mg * cph;
                Si[(size_t)m * DD + d] = mg * sph;
            }
        }
}

// ---------------- X/Y pack (fallback when norm can't persist X/Y) ---------------- (R12-proven)
__global__ __launch_bounds__(256) void k_xy(const float* __restrict__ Sr, const float* __restrict__ Si,
        const float* __restrict__ cd, const float* __restrict__ sd,
        unsigned short* X, unsigned short* Y,
        const int* __restrict__ active) {
    if (*active == 0) return;
    const int r = blockIdx.x, t = threadIdx.x;
    const size_t base = (size_t)r * DD + 2 * t;
    const float2 s_r = *(const float2*)(Sr + base);
    const float2 s_i = *(const float2*)(Si + base);
    const float2 c2  = *(const float2*)(cd + 2 * t);
    const float2 s2  = *(const float2*)(sd + 2 * t);
    unsigned short* xr = X + (size_t)r * KA;
    unsigned short* yr = Y + (size_t)r * KA;
    const float srv[2] = {s_r.x, s_r.y}, siv[2] = {s_i.x, s_i.y};
    const float cv_[2] = {c2.x, c2.y},  sv_[2] = {s2.x, s2.y};
    ushort2 xh_r, xh_i, xl_r, xl_i, yh_r, yh_i, yl_r, yl_i;
    unsigned short* o[8] = {(unsigned short*)&xh_r, (unsigned short*)&xh_i,
                            (unsigned short*)&xl_r, (unsigned short*)&xl_i,
                            (unsigned short*)&yh_r, (unsigned short*)&yh_i,
                            (unsigned short*)&yl_r, (unsigned short*)&yl_i};
#pragma unroll
    for (int e = 0; e < 2; e++) {
        const unsigned short hr = f2bf(srv[e]);
        const unsigned short hi_ = f2bf(siv[e]);
        o[0][e] = hr;  o[2][e] = f2bf(srv[e] - bf2f(hr));
        o[1][e] = hi_; o[3][e] = f2bf(siv[e] - bf2f(hi_));
        const float krr = srv[e] * cv_[e] + siv[e] * sv_[e];
        const float kri = siv[e] * cv_[e] - srv[e] * sv_[e];
        const unsigned short yh1 = f2bf(krr);
        const unsigned short yh2 = f2bf(kri);
        o[4][e] = yh1; o[6][e] = f2bf(krr - bf2f(yh1));
        o[5][e] = yh2; o[7][e] = f2bf(kri - bf2f(yh2));
    }
    *(ushort2*)(xr + 2 * t)        = xh_r;
    *(ushort2*)(xr + 512 + 2 * t)  = xh_i;
    *(ushort2*)(xr + 1024 + 2 * t) = xl_r;
    *(ushort2*)(xr + 1536 + 2 * t) = xl_i;
    *(ushort2*)(yr + 2 * t)        = yh_r;
    *(ushort2*)(yr + 512 + 2 * t)  = yh_i;
    *(ushort2*)(yr + 1024 + 2 * t) = yl_r;
    *(ushort2*)(yr + 1536 + 2 * t) = yl_i;
}

// ---------------- fused score+softmax: S=scale*(X@Y^T) 3-term, row softmax, bf16-split out ----------------
// M-tile 64 x full 256 q. 48 MFMA per barrier-pair; per-row softmax over (tc, lane15).
__global__ __launch_bounds__(256) void k_score_sm(const unsigned short* __restrict__ X,
        const unsigned short* __restrict__ Y,
        unsigned short* __restrict__ Asp, const int* __restrict__ active) {
    if (*active == 0) return;
    __shared__ short XH[64][32], XL[64][32];
    __shared__ short YH[256][32], YL[256][32];
    const int t = threadIdx.x;
    const int w = t >> 6, L = t & 63;
    const int lane15 = L & 15, quad = L >> 4;
    const int bm = blockIdx.x * 64;              // chunk-local row base
    const int yb = ((int)blockIdx.x >> 2) * 256; // sample's Y rows
    const int gr = t >> 2, ch = (t & 3) * 8;
    short* XHw = &XH[0][0] + w * 512;
    short* XLw = &XL[0][0] + w * 512;
    short* YHw = &YH[0][0] + w * 512;
    short* YLw = &YL[0][0] + w * 512;
    f32x4 acc[16] = {};
    for (int k0 = 0; k0 < 1024; k0 += 32) {
        __syncthreads();
        gl2lds16(X + (size_t)(bm + gr) * KA + k0 + ch,        XHw);
        gl2lds16(X + (size_t)(bm + gr) * KA + 1024 + k0 + ch, XLw);
#pragma unroll
        for (int s = 0; s < 4; s++) {
            gl2lds16(Y + (size_t)(yb + s * 64 + gr) * KA + k0 + ch,        YHw + s * 2048);
            gl2lds16(Y + (size_t)(yb + s * 64 + gr) * KA + 1024 + k0 + ch, YLw + s * 2048);
        }
        __syncthreads();
        const bf16x8 xh = *(const bf16x8*)&XH[w * 16 + lane15][quad * 8];
        const bf16x8 xl = *(const bf16x8*)&XL[w * 16 + lane15][quad * 8];
#pragma unroll
        for (int tc = 0; tc < 16; tc++) {
            const bf16x8 yh = *(const bf16x8*)&YH[tc * 16 + lane15][quad * 8];
            acc[tc] = __builtin_amdgcn_mfma_f32_16x16x32_bf16(xh, yh, acc[tc], 0, 0, 0);
            acc[tc] = __builtin_amdgcn_mfma_f32_16x16x32_bf16(xl, yh, acc[tc], 0, 0, 0);
            const bf16x8 yl = *(const bf16x8*)&YL[tc * 16 + lane15][quad * 8];
            acc[tc] = __builtin_amdgcn_mfma_f32_16x16x32_bf16(xh, yl, acc[tc], 0, 0, 0);
        }
    }
    // softmax epilogue: row = bm + w*16 + quad*4 + r; q = tc*16 + lane15
#pragma unroll
    for (int tc = 0; tc < 16; tc++) acc[tc] *= SCALE_F;
#pragma unroll
    for (int r = 0; r < 4; r++) {
        float mx = acc[0][r];
#pragma unroll
        for (int tc = 1; tc < 16; tc++) mx = fmaxf(mx, acc[tc][r]);
#pragma unroll
        for (int off = 8; off; off >>= 1) mx = fmaxf(mx, __shfl_xor(mx, off, 64));
        float s = 0.f;
        float e[16];
#pragma unroll
        for (int tc = 0; tc < 16; tc++) { e[tc] = __expf(acc[tc][r] - mx); s += e[tc]; }
#pragma unroll
        for (int off = 8; off; off >>= 1) s += __shfl_xor(s, off, 64);
        const float inv = 1.0f / s;
        const int row = bm + w * 16 + quad * 4 + r;
        unsigned short* o = Asp + (size_t)row * 512;
#pragma unroll
        for (int tc = 0; tc < 16; tc++) {
            const float p = e[tc] * inv;
            const unsigned short h = f2bf(p);
            o[tc * 16 + lane15] = h;
            o[256 + tc * 16 + lane15] = f2bf(p - bf2f(h));
        }
    }
}

// ---------------- attn_out via split-bf16 MFMA (3-term), fused v-rot + prev-add epilogue ---------------- (R1-proven)
__global__ __launch_bounds__(256) void k_attnout_mfma(const unsigned short* __restrict__ Asp,
        const unsigned short* __restrict__ X,
        const float* __restrict__ Sr, const float* __restrict__ Si,
        const float* __restrict__ cv, const float* __restrict__ sv,
        unsigned short* __restrict__ A2, const int* __restrict__ active) {
    if (*active == 0) return;
    __shared__ short AhT[128][32];
    __shared__ short AlT[128][32];
    __shared__ short BH[128][40];   // +8 pad: 80B row stride -> b128 r/w at the bank floor
    __shared__ short BL[128][40];
    const int t = threadIdx.x;
    const int w = t >> 6, L = t & 63;
    const int lane15 = L & 15, quad = L >> 4;
    const int bm = blockIdx.y * 128;          // chunk-local row base
    const int bn = blockIdx.x * 64;           // d base (0..448)
    const int sample = blockIdx.y >> 1;       // chunk-local sample
    const int gr = t >> 2, ch = (t & 3) * 8;
    short* AhW0 = &AhT[0][0] + w * 512;
    short* AhW1 = AhW0 + 64 * 32;
    short* AlW0 = &AlT[0][0] + w * 512;
    short* AlW1 = AlW0 + 64 * 32;
    const int nn = t & 127, kh = t >> 7;
    const unsigned short* Bsrc = X + (size_t)sample * PP * KA
                               + ((nn < 64) ? (bn + nn) : (512 + bn + nn - 64));
    f32x4 acc[2][8] = {};
    for (int q0 = 0; q0 < PP; q0 += 32) {
        __syncthreads();
        gl2lds16(Asp + (size_t)(bm + gr) * 512      + q0 + ch,       AhW0);
        gl2lds16(Asp + (size_t)(bm + 64 + gr) * 512 + q0 + ch,       AhW1);
        gl2lds16(Asp + (size_t)(bm + gr) * 512      + 256 + q0 + ch, AlW0);
        gl2lds16(Asp + (size_t)(bm + 64 + gr) * 512 + 256 + q0 + ch, AlW1);
#pragma unroll
        for (int kg = 0; kg < 2; kg++) {
            const int qb = kh * 16 + kg * 8;
            bf16x8 hh, ll;
#pragma unroll
            for (int j = 0; j < 8; j++) {
                const size_t o = (size_t)(q0 + qb + j) * KA;
                hh[j] = (short)Bsrc[o];
                ll[j] = (short)Bsrc[o + 1024];
            }
            *(bf16x8*)&BH[nn][qb] = hh;
            *(bf16x8*)&BL[nn][qb] = ll;
        }
        __syncthreads();
        bf16x8 bh[8];
#pragma unroll
        for (int tc = 0; tc < 8; tc++)
            bh[tc] = *(const bf16x8*)&BH[tc * 16 + lane15][quad * 8];
        bf16x8 afh[2];
#pragma unroll
        for (int tr = 0; tr < 2; tr++) {
            afh[tr] = *(const bf16x8*)&AhT[w * 32 + tr * 16 + lane15][quad * 8];
            const bf16x8 afl = *(const bf16x8*)&AlT[w * 32 + tr * 16 + lane15][quad * 8];
#pragma unroll
            for (int tc = 0; tc < 8; tc++)
                acc[tr][tc] = __builtin_amdgcn_mfma_f32_16x16x32_bf16(afh[tr], bh[tc], acc[tr][tc], 0, 0, 0);
#pragma unroll
            for (int tc = 0; tc < 8; tc++)
                acc[tr][tc] = __builtin_amdgcn_mfma_f32_16x16x32_bf16(afl, bh[tc], acc[tr][tc], 0, 0, 0);
        }
#pragma unroll
        for (int tc = 0; tc < 8; tc++) {
            const bf16x8 bl = *(const bf16x8*)&BL[tc * 16 + lane15][quad * 8];
            acc[0][tc] = __builtin_amdgcn_mfma_f32_16x16x32_bf16(afh[0], bl, acc[0][tc], 0, 0, 0);
            acc[1][tc] = __builtin_amdgcn_mfma_f32_16x16x32_bf16(afh[1], bl, acc[1][tc], 0, 0, 0);
        }
    }
#pragma unroll
    for (int tr = 0; tr < 2; tr++) {
#pragma unroll
        for (int tc = 0; tc < 4; tc++) {
            const int d = bn + tc * 16 + lane15;
            const float cvd = cv[d], svd = sv[d];
#pragma unroll
            for (int r = 0; r < 4; r++) {
                const int m = bm + w * 32 + tr * 16 + quad * 4 + r;  // chunk-local row
                const float wr = acc[tr][tc][r];
                const float wi = acc[tr][tc + 4][r];
                const float tr_ = Sr[(size_t)m * DD + d] + (wr * cvd - wi * svd);
                const float ti_ = Si[(size_t)m * DD + d] + (wr * svd + wi * cvd);
                const unsigned short rh = f2bf(tr_);
                const unsigned short ih = f2bf(ti_);
                unsigned short* arow = A2 + (size_t)m * KA;
                arow[d]        = rh;
                arow[512 + d]  = ih;
                arow[1024 + d] = f2bf(tr_ - bf2f(rh));
                arow[1536 + d] = f2bf(ti_ - bf2f(ih));
            }
        }
    }
}

// ---------------- ff via split-bf16 MFMA, 48-MFMA phases, Bt2=[hi|lo] ----------------
__global__ __launch_bounds__(256) void k_ff_mfma2(const unsigned short* __restrict__ A2,
        const unsigned short* __restrict__ Bt2,
        float* __restrict__ U, const int* __restrict__ active) {
    if (*active == 0) return;
    __shared__ short AH[128][32], AL[128][32];
    __shared__ short BH[128][32], BL[128][32];
    const int t = threadIdx.x;
    const int w = t >> 6, L = t & 63;
    const int lane15 = L & 15, quad = L >> 4;
    const int bm = blockIdx.y * 128, bn = blockIdx.x * 128;
    const int gr = t >> 2, ch = (t & 3) * 8;
    short* AHw = &AH[0][0] + w * 512;
    short* ALw = &AL[0][0] + w * 512;
    short* BHw = &BH[0][0] + w * 512;
    short* BLw = &BL[0][0] + w * 512;
    f32x4 acc[2][8] = {};
    for (int k0 = 0; k0 < 1024; k0 += 32) {
        __syncthreads();
        gl2lds16(A2  + (size_t)(bm + gr) * KA       + k0 + ch,        AHw);
        gl2lds16(A2  + (size_t)(bm + 64 + gr) * KA  + k0 + ch,        AHw + 64 * 32);
        gl2lds16(A2  + (size_t)(bm + gr) * KA       + 1024 + k0 + ch, ALw);
        gl2lds16(A2  + (size_t)(bm + 64 + gr) * KA  + 1024 + k0 + ch, ALw + 64 * 32);
        gl2lds16(Bt2 + (size_t)(bn + gr) * KB2      + k0 + ch,        BHw);
        gl2lds16(Bt2 + (size_t)(bn + 64 + gr) * KB2 + k0 + ch,        BHw + 64 * 32);
        gl2lds16(Bt2 + (size_t)(bn + gr) * KB2      + 1024 + k0 + ch, BLw);
        gl2lds16(Bt2 + (size_t)(bn + 64 + gr) * KB2 + 1024 + k0 + ch, BLw + 64 * 32);
        __syncthreads();
        bf16x8 ah[2], al[2];
#pragma unroll
        for (int tr = 0; tr < 2; tr++) {
            ah[tr] = *(const bf16x8*)&AH[w * 32 + tr * 16 + lane15][quad * 8];
            al[tr] = *(const bf16x8*)&AL[w * 32 + tr * 16 + lane15][quad * 8];
        }
#pragma unroll
        for (int tc = 0; tc < 8; tc++) {
            const bf16x8 bh = *(const bf16x8*)&BH[tc * 16 + lane15][quad * 8];
            acc[0][tc] = __builtin_amdgcn_mfma_f32_16x16x32_bf16(ah[0], bh, acc[0][tc], 0, 0, 0);
            acc[1][tc] = __builtin_amdgcn_mfma_f32_16x16x32_bf16(ah[1], bh, acc[1][tc], 0, 0, 0);
            acc[0][tc] = __builtin_amdgcn_mfma_f32_16x16x32_bf16(al[0], bh, acc[0][tc], 0, 0, 0);
            acc[1][tc] = __builtin_amdgcn_mfma_f32_16x16x32_bf16(al[1], bh, acc[1][tc], 0, 0, 0);
            const bf16x8 bl = *(const bf16x8*)&BL[tc * 16 + lane15][quad * 8];
            acc[0][tc] = __builtin_amdgcn_mfma_f32_16x16x32_bf16(ah[0], bl, acc[0][tc], 0, 0, 0);
            acc[1][tc] = __builtin_amdgcn_mfma_f32_16x16x32_bf16(ah[1], bl, acc[1][tc], 0, 0, 0);
        }
    }
#pragma unroll
    for (int tr = 0; tr < 2; tr++)
#pragma unroll
        for (int tc = 0; tc < 8; tc++) {
            const int n = bn + tc * 16 + lane15;
            const int mbase = bm + w * 32 + tr * 16 + quad * 4;
#pragma unroll
            for (int r = 0; r < 4; r++)
                U[(size_t)(mbase + r) * NK + n] = acc[tr][tc][r];
        }
}

// ---------------- complex_norm + commit + partial + fused X/Y pack ----------------
// NOTE: X overlays U byte-exactly per row; every X store data-depends on all U loads
// (via the cross-lane mean/var reduction), so in-place is safe. No __restrict__ on U/X/Y.
__global__ __launch_bounds__(256) void k_norm(const float* U,
        float* __restrict__ Sr, float* __restrict__ Si,
        float* __restrict__ part,
        unsigned short* X, unsigned short* Y,
        const float* __restrict__ cd, const float* __restrict__ sd,
        const int wxy, const int* __restrict__ active) {
    if (*active == 0) return;
    __shared__ float red[8];
    const int t = threadIdx.x, rt = t >> 6, L = t & 63;
    const int row = blockIdx.x * 4 + rt;
    const size_t ub = (size_t)row * NK;
    const size_t base = (size_t)row * DD;
    const float4 ur0 = *(const float4*)(U + ub + 4 * L);
    const float4 ur1 = *(const float4*)(U + ub + 256 + 4 * L);
    const float4 ui0 = *(const float4*)(U + ub + 512 + 4 * L);
    const float4 ui1 = *(const float4*)(U + ub + 768 + 4 * L);
    const float4 pr0 = *(const float4*)(Sr + base + 4 * L);
    const float4 pr1 = *(const float4*)(Sr + base + 256 + 4 * L);
    const float4 pi0 = *(const float4*)(Si + base + 4 * L);
    const float4 pi1 = *(const float4*)(Si + base + 256 + 4 * L);
    const float urr[8] = {ur0.x, ur0.y, ur0.z, ur0.w, ur1.x, ur1.y, ur1.z, ur1.w};
    const float uii[8] = {ui0.x, ui0.y, ui0.z, ui0.w, ui1.x, ui1.y, ui1.z, ui1.w};
    float mg[8], msum = 0.f;
#pragma unroll
    for (int e = 0; e < 8; e++) {
        mg[e] = sqrtf(urr[e] * urr[e] + uii[e] * uii[e]);
        msum += mg[e];
    }
#pragma unroll
    for (int off = 32; off; off >>= 1) msum += __shfl_xor(msum, off, 64);
    const float mean = msum * (1.0f / 512.0f);
    float vs = 0.f;
#pragma unroll
    for (int e = 0; e < 8; e++) { const float d = mg[e] - mean; vs += d * d; }
#pragma unroll
    for (int off = 32; off; off >>= 1) vs += __shfl_xor(vs, off, 64);
    const float istd = 1.0f / (sqrtf(vs * (1.0f / 511.0f)) + 1e-5f);
    float nr[8], ni[8];
#pragma unroll
    for (int e = 0; e < 8; e++) {
        const float sc = tanhf((mg[e] - mean) * istd) / (mg[e] + 1e-5f);
        nr[e] = urr[e] * sc; ni[e] = uii[e] * sc;
    }
    const float prr[8] = {pr0.x, pr0.y, pr0.z, pr0.w, pr1.x, pr1.y, pr1.z, pr1.w};
    const float pii[8] = {pi0.x, pi0.y, pi0.z, pi0.w, pi1.x, pi1.y, pi1.z, pi1.w};
    float dd = 0.f, nn = 0.f;
#pragma unroll
    for (int e = 0; e < 8; e++) {
        const float dr = nr[e] - prr[e], di = ni[e] - pii[e];
        dd += dr * dr + di * di;
        nn += nr[e] * nr[e] + ni[e] * ni[e];
    }
    *(float4*)(Sr + base + 4 * L)       = make_float4(nr[0], nr[1], nr[2], nr[3]);
    *(float4*)(Sr + base + 256 + 4 * L) = make_float4(nr[4], nr[5], nr[6], nr[7]);
    *(float4*)(Si + base + 4 * L)       = make_float4(ni[0], ni[1], ni[2], ni[3]);
    *(float4*)(Si + base + 256 + 4 * L) = make_float4(ni[4], ni[5], ni[6], ni[7]);
    if (wxy) {
        unsigned short* xr = X + (size_t)row * KA;
        unsigned short* yr = Y + (size_t)row * KA;
        const float4 c0 = *(const float4*)(cd + 4 * L);
        const float4 c1 = *(const float4*)(cd + 256 + 4 * L);
        const float4 s0 = *(const float4*)(sd + 4 * L);
        const float4 s1 = *(const float4*)(sd + 256 + 4 * L);
        const float cdv[8] = {c0.x, c0.y, c0.z, c0.w, c1.x, c1.y, c1.z, c1.w};
        const float sdv[8] = {s0.x, s0.y, s0.z, s0.w, s1.x, s1.y, s1.z, s1.w};
        ushort4 xhr[2], xhi[2], xlr[2], xli[2], yhr[2], yhi[2], ylr[2], yli[2];
#pragma unroll
        for (int e = 0; e < 8; e++) {
            const int g = e >> 2, j = e & 3;
            const unsigned short hr = f2bf(nr[e]);
            const unsigned short hi_ = f2bf(ni[e]);
            ((unsigned short*)&xhr[g])[j] = hr;
            ((unsigned short*)&xlr[g])[j] = f2bf(nr[e] - bf2f(hr));
            ((unsigned short*)&xhi[g])[j] = hi_;
            ((unsigned short*)&xli[g])[j] = f2bf(ni[e] - bf2f(hi_));
            const float krr = nr[e] * cdv[e] + ni[e] * sdv[e];
            const float kri = ni[e] * cdv[e] - nr[e] * sdv[e];
            const unsigned short k1 = f2bf(krr);
            const unsigned short k2 = f2bf(kri);
            ((unsigned short*)&yhr[g])[j] = k1;
            ((unsigned short*)&ylr[g])[j] = f2bf(krr - bf2f(k1));
            ((unsigned short*)&yhi[g])[j] = k2;
            ((unsigned short*)&yli[g])[j] = f2bf(kri - bf2f(k2));
        }
        *(ushort4*)(xr + 4 * L)        = xhr[0]; *(ushort4*)(xr + 256 + 4 * L)  = xhr[1];
        *(ushort4*)(xr + 512 + 4 * L)  = xhi[0]; *(ushort4*)(xr + 768 + 4 * L)  = xhi[1];
        *(ushort4*)(xr + 1024 + 4 * L) = xlr[0]; *(ushort4*)(xr + 1280 + 4 * L) = xlr[1];
        *(ushort4*)(xr + 1536 + 4 * L) = xli[0]; *(ushort4*)(xr + 1792 + 4 * L) = xli[1];
        *(ushort4*)(yr + 4 * L)        = yhr[0]; *(ushort4*)(yr + 256 + 4 * L)  = yhr[1];
        *(ushort4*)(yr + 512 + 4 * L)  = yhi[0]; *(ushort4*)(yr + 768 + 4 * L)  = yhi[1];
        *(ushort4*)(yr + 1024 + 4 * L) = ylr[0]; *(ushort4*)(yr + 1280 + 4 * L) = ylr[1];
        *(ushort4*)(yr + 1536 + 4 * L) = yli[0]; *(ushort4*)(yr + 1792 + 4 * L) = yli[1];
    }
#pragma unroll
    for (int off = 32; off; off >>= 1) {
        dd += __shfl_xor(dd, off, 64);
        nn += __shfl_xor(nn, off, 64);
    }
    if (L == 0) { red[rt] = dd; red[4 + rt] = nn; }
    __syncthreads();
    if (t == 0)
        *(float2*)(part + 2 * blockIdx.x) =
            make_float2(red[0] + red[1] + red[2] + red[3],
                        red[4] + red[5] + red[6] + red[7]);
}

// ---------------- convergence flag: reduce all NSLOT partials ----------------
__global__ __launch_bounds__(256) void k_flag(const float* __restrict__ part, int* __restrict__ active) {
    __shared__ float red[8];
    const int t = threadIdx.x, rt = t >> 6, L = t & 63;
    float dd = 0.f, nn = 0.f;
    for (int i = t; i < NSLOT; i += 256) {
        const float2 p = *(const float2*)(part + 2 * i);
        dd += p.x; nn += p.y;
    }
#pragma unroll
    for (int off = 32; off; off >>= 1) {
        dd += __shfl_xor(dd, off, 64);
        nn += __shfl_xor(nn, off, 64);
    }
    if (L == 0) { red[rt] = dd; red[4 + rt] = nn; }
    __syncthreads();
    if (t == 0) {
        const float d = red[0] + red[1] + red[2] + red[3];
        const float n = red[4] + red[5] + red[6] + red[7];
        const float diff = sqrtf(d) / (sqrtf(n) + 1e-8f);
        const int a = *active;
        *active = (a && (diff >= 1e-3f)) ? 1 : 0;
    }
}

// ---------------- mean over P ----------------
__global__ __launch_bounds__(256) void k_pool(const float* __restrict__ Sr, const float* __restrict__ Si,
        float* __restrict__ Pr, float* __restrict__ Pi) {
    const int gid = blockIdx.x * 256 + threadIdx.x;
    const int b = gid >> 9, d = gid & 511;
    const size_t base = (size_t)b * PP * DD + d;
    float sr = 0.f, si = 0.f;
    for (int p = 0; p < PP; p++) {
        sr += Sr[base + (size_t)p * DD];
        si += Si[base + (size_t)p * DD];
    }
    Pr[gid] = sr * (1.0f / 256.0f);
    Pi[gid] = si * (1.0f / 256.0f);
}

// ---------------- logits ----------------
__global__ __launch_bounds__(64) void k_logits(const float* __restrict__ Pr, const float* __restrict__ Pi,
        const float* __restrict__ Wr, const float* __restrict__ br,
        const float* __restrict__ Wi, const float* __restrict__ bi,
        float* __restrict__ out) {
    const int b = blockIdx.x;
    const int lane = threadIdx.x;
    for (int c = 0; c < CC; c++) {
        float acc = 0.f;
#pragma unroll
        for (int k = 0; k < 8; k++) {
            const int d = lane + 64 * k;
            acc += Pr[b * DD + d] * Wr[c * DD + d] + Pi[b * DD + d] * Wi[c * DD + d];
        }
#pragma unroll
        for (int off = 32; off; off >>= 1) acc += __shfl_xor(acc, off, 64);
        if (lane == 0) out[b * CC + c] = acc + br[c] + bi[c];
    }
}

extern "C" void kernel_launch(void* const* d_in, const int* in_sizes, int n_in,
                              void* d_out, int out_size, void* d_ws, size_t ws_size,
                              hipStream_t stream) {
    const float* x     = (const float*)d_in[0];
    const float* Wp    = (const float*)d_in[1];
    const float* bp    = (const float*)d_in[2];
    const float* q_rot = (const float*)d_in[3];
    const float* k_rot = (const float*)d_in[4];
    const float* v_rot = (const float*)d_in[5];
    const float* ffr   = (const float*)d_in[6];
    const float* ffi   = (const float*)d_in[7];
    const float* Wr    = (const float*)d_in[8];
    const float* br    = (const float*)d_in[9];
    const float* Wi    = (const float*)d_in[10];
    const float* bi    = (const float*)d_in[11];
    float* out = (float*)d_out;

    float* ws = (float*)d_ws;
    const size_t plane = (size_t)MTOT * DD;      // 16,777,216 floats
    const size_t sline = (size_t)PP * DD;

    float* freq = ws;                  // 512
    float* cd   = freq + DD;
    float* sd   = cd + DD;
    float* cv   = sd + DD;
    float* sv   = cv + DD;
    int*   active = (int*)(sv + DD);   // 1
    float* Pr = ws + 4096;             // 65536
    float* Pi = Pr + (size_t)BB * DD;  // 65536
    float* part = Pi + (size_t)BB * DD;        // 2*NSLOT = 16384 floats
    float* Sr = part + 2 * NSLOT;              // fp32 state (128 MiB)
    float* Si = Sr + plane;
    unsigned short* Bt2 = (unsigned short*)(Si + plane);   // 1024x2048 bf16 (4 MB)
    unsigned short* Wt  = Bt2 + (size_t)NK * KB2;          // 512x512 bf16 (0.5 MB), inside 6MB hole
    float* chunkbase = Si + plane + (size_t)NK * 3072 / 2; // 6MB hole reserved (Bt2 + Wt fit)

    const size_t fixed_f = (4096 + 2 * (size_t)BB * DD + 2 * NSLOT) + 2 * plane + (size_t)NK * 3072 / 2;
    // per-sample: X/U overlay (1 MB) + Y/A2 overlay (1 MB) + Asp (256 KB) = 2.25 MB
    const size_t perC_f = (size_t)PP * NK * 2 + (size_t)PP * 256;   // 589824 floats

    int C = BB;
    while (C > 1 && (fixed_f + (size_t)C * perC_f) * 4ull > ws_size) C >>= 1;
    const int fullXY = (C == BB);      // X/Y persist across iterations -> norm packs them
    const int mfmaInit = (C >= 32);    // Xp (67 MB) fits in the chunk region

    float* U = chunkbase;                                       // C x 256 x 1024 fp32
    unsigned short* X  = (unsigned short*)chunkbase;            // overlay: X dead before ff writes U
    float* Yf = chunkbase + (size_t)C * PP * NK;
    unsigned short* Y  = (unsigned short*)Yf;                   // C x 256 x 2048 bf16
    unsigned short* A2 = Y;                                     // overlay: Y dead after k_score_sm
    unsigned short* Asp = (unsigned short*)(Yf + (size_t)C * PP * NK);  // C x 256 x 512 bf16
    unsigned short* Xp = (unsigned short*)chunkbase;            // init staging overlay (dead pre-loop)

    k_setup<<<1, 512, 0, stream>>>(q_rot, k_rot, v_rot, freq, cd, sd, cv, sv, active);
    k_prep2<<<NK, 256, 0, stream>>>(ffr, ffi, Bt2);
    if (mfmaInit) {
        k_packx<<<MTOT, 256, 0, stream>>>(x, Xp);
        k_wpack<<<DD, 256, 0, stream>>>(Wp, Wt);
        k_init_mfma<<<dim3(DD / 128, MTOT / 128), 256, 0, stream>>>(Xp, Wt, bp, freq, Sr, Si);
    } else {
        k_init<<<dim3(DD / 64, MTOT / 64), 256, 0, stream>>>(x, Wp, bp, freq, Sr, Si);
    }

    for (int it = 0; it < 4; ++it) {
        for (int c0 = 0; c0 < BB; c0 += C) {
            float* Sr_c = Sr + (size_t)c0 * sline;
            float* Si_c = Si + (size_t)c0 * sline;
            float* part_c = part + (size_t)c0 * (PP / 4) * 2;
            if (!fullXY || it == 0)
                k_xy<<<C * PP, 256, 0, stream>>>(Sr_c, Si_c, cd, sd, X, Y, active);
            k_score_sm<<<C * 4, 256, 0, stream>>>(X, Y, Asp, active);
            k_attnout_mfma<<<dim3(8, C * 2), 256, 0, stream>>>(Asp, X, Sr_c, Si_c, cv, sv, A2, active);
            k_ff_mfma2<<<dim3(NK / 128, C * 2), 256, 0, stream>>>(A2, Bt2, U, active);
            k_norm<<<C * (PP / 4), 256, 0, stream>>>(U, Sr_c, Si_c, part_c, X, Y, cd, sd, fullXY, active);
        }
        k_flag<<<1, 256, 0, stream>>>(part, active);
    }

    k_pool<<<BB * DD / 256, 256, 0, stream>>>(Sr, Si, Pr, Pi);
    k_logits<<<BB, 64, 0, stream>>>(Pr, Pi, Wr, br, Wi, bi, out);
}

// Round 3
// 3124.032 us; speedup vs baseline: 1.3381x; 1.0460x over previous
//
#include <hip/hip_runtime.h>
#include <math.h>

#define BB   128
#define PP   256
#define PIX_ 256
#define DD   512
#define CC   10
#define MTOT (BB*PP)   // 32768
#define NK   1024      // packed complex N for the ff GEMM
#define KA   2048      // A2 / X / Y row length (hi|lo)
#define KB2  2048      // Bt2 row length (hi|lo)
#define NSLOT (MTOT/4) // 8192 partial slots (one per norm block, whole batch)

static constexpr float SCALE_F = 0.35355339059327373f; // 8/sqrt(512)
static constexpr float PI_F    = 3.14159265358979323846f;

typedef short bf16x8 __attribute__((ext_vector_type(8)));
typedef float f32x4  __attribute__((ext_vector_type(4)));

__device__ __forceinline__ unsigned short f2bf(float f) {
    union { float f; unsigned u; } v; v.f = f;
    unsigned r = v.u + 0x7FFF + ((v.u >> 16) & 1);   // RNE
    return (unsigned short)(r >> 16);
}
__device__ __forceinline__ float bf2f(unsigned short h) {
    union { unsigned u; float f; } v; v.u = ((unsigned)h) << 16;
    return v.f;
}

// async global->LDS, 16B per lane; LDS dest = wave-uniform base + lane*16B (m97 pattern)
typedef __attribute__((address_space(3))) unsigned lds_u32;
typedef __attribute__((address_space(1))) const unsigned glb_u32;
__device__ __forceinline__ void gl2lds16(const unsigned short* g, short* l) {
    __builtin_amdgcn_global_load_lds((glb_u32*)g, (lds_u32*)l, 16, 0, 0);
}

// ---------------- setup ----------------
__global__ void k_setup(const float* __restrict__ q_rot, const float* __restrict__ k_rot,
                        const float* __restrict__ v_rot,
                        float* __restrict__ freq, float* __restrict__ cd, float* __restrict__ sd,
                        float* __restrict__ cv, float* __restrict__ sv,
                        int* __restrict__ active) {
    int t = threadIdx.x;
    if (t < DD) {
        freq[t] = expf(-(float)t * (9.210340371976184f / 512.0f)); // 10000^(-d/512)
        float dl = q_rot[t] - k_rot[t];
        cd[t] = cosf(dl);       sd[t] = sinf(dl);
        cv[t] = cosf(v_rot[t]); sv[t] = sinf(v_rot[t]);
    }
    if (t == 0) *active = 1;
}

// ---------------- build Bt2[n][0:2048] = [Bhi | Blo] (k-major) ----------------
__global__ __launch_bounds__(256) void k_prep2(const float* __restrict__ Fr, const float* __restrict__ Fi,
                                               unsigned short* __restrict__ Bt2) {
    const int n = blockIdx.x;           // 0..1023
    const int t = threadIdx.x;
    unsigned short* row = Bt2 + (size_t)n * KB2;
#pragma unroll
    for (int j4 = 0; j4 < 4; j4++) {
        const int j = j4 * 256 + t;
        float v;
        if (n < 512) v = (j < 512) ? Fr[(size_t)j * DD + n] : -Fi[(size_t)(j - 512) * DD + n];
        else         v = (j < 512) ? Fi[(size_t)j * DD + (n - 512)] : Fr[(size_t)(j - 512) * DD + (n - 512)];
        const unsigned short hi = f2bf(v);
        row[j] = hi;
        row[NK + j] = f2bf(v - bf2f(hi));
    }
}

// ---------------- pack x rows -> [hi(256)|lo(256)] ----------------
__global__ __launch_bounds__(256) void k_packx(const float* __restrict__ x, unsigned short* __restrict__ Xp) {
    const int r = blockIdx.x, t = threadIdx.x;
    const float v = x[(size_t)r * PIX_ + t];
    const unsigned short h = f2bf(v);
    Xp[(size_t)r * 512 + t] = h;
    Xp[(size_t)r * 512 + 256 + t] = f2bf(v - bf2f(h));
}

// ---------------- pack Wp rows -> [hi(256)|lo(256)] ----------------
__global__ __launch_bounds__(256) void k_wpack(const float* __restrict__ Wp, unsigned short* __restrict__ Wt) {
    const int d = blockIdx.x, t = threadIdx.x;
    const float v = Wp[(size_t)d * PIX_ + t];
    const unsigned short h = f2bf(v);
    Wt[(size_t)d * 512 + t] = h;
    Wt[(size_t)d * 512 + 256 + t] = f2bf(v - bf2f(h));
}

#define SCAT4(TILE, V4) do { TILE[lk+0][lrow]=(V4).x; TILE[lk+1][lrow]=(V4).y; \
                             TILE[lk+2][lrow]=(V4).z; TILE[lk+3][lrow]=(V4).w; } while(0)

// ---------------- init (fp32 fallback, small-ws path) ---------------- (R2-proven)
__global__ __launch_bounds__(256) void k_init(const float* __restrict__ x,
        const float* __restrict__ Wp, const float* __restrict__ bp,
        const float* __restrict__ freq,
        float* __restrict__ Sr, float* __restrict__ Si) {
    __shared__ float As[16][68];
    __shared__ float Bs[16][68];
    const int bm = blockIdx.y * 64, bn = blockIdx.x * 64;
    const int t = threadIdx.x, tx = t & 15, ty = t >> 4;
    const int lrow = t >> 2, lk = (t & 3) * 4;
    float acc[4][4] = {};
    for (int k0 = 0; k0 < PIX_; k0 += 16) {
        const float4 a4 = *(const float4*)(x  + (size_t)(bm + lrow) * PIX_ + k0 + lk);
        const float4 b4 = *(const float4*)(Wp + (size_t)(bn + lrow) * PIX_ + k0 + lk);
        __syncthreads();
        SCAT4(As, a4);
        SCAT4(Bs, b4);
        __syncthreads();
#pragma unroll
        for (int kk = 0; kk < 16; ++kk) {
            const float4 av = *(const float4*)&As[kk][ty * 4];
            const float4 bv = *(const float4*)&Bs[kk][tx * 4];
            const float a[4] = {av.x, av.y, av.z, av.w};
            const float b[4] = {bv.x, bv.y, bv.z, bv.w};
#pragma unroll
            for (int i = 0; i < 4; i++)
#pragma unroll
                for (int j = 0; j < 4; j++) acc[i][j] = fmaf(a[i], b[j], acc[i][j]);
        }
    }
#pragma unroll
    for (int i = 0; i < 4; i++) {
        const int m = bm + ty * 4 + i;
        const int p = m & 255;
        float4 vr, vi;
        float* pvr = (float*)&vr; float* pvi = (float*)&vi;
#pragma unroll
        for (int j = 0; j < 4; j++) {
            const int d = bn + tx * 4 + j;
            const float mg = tanhf(acc[i][j] + bp[d]);
            const float ph = (float)p * freq[d] * PI_F;
            float sph, cph; sincosf(ph, &sph, &cph);
            pvr[j] = mg * cph; pvi[j] = mg * sph;
        }
        *(float4*)(Sr + (size_t)m * DD + bn + tx * 4) = vr;
        *(float4*)(Si + (size_t)m * DD + bn + tx * 4) = vi;
    }
}

// ---------------- init via split-bf16 MFMA (3-term K=256), tanh+phase epilogue ----------------
// R3: LDS-transpose epilogue (256B-contiguous float4 stores; kills 5.5x write amplification)
//     + grid flipped so same-row d-tiles share an XCD.
__global__ __launch_bounds__(256) void k_init_mfma(const unsigned short* __restrict__ Xp,
        const unsigned short* __restrict__ Wt, const float* __restrict__ bp,
        const float* __restrict__ freq,
        float* __restrict__ Sr, float* __restrict__ Si) {
    __shared__ short AH[128][32], AL[128][32];
    __shared__ short BH[128][32], BL[128][32];
    __shared__ float TBr[128][68];
    __shared__ float TBi[128][68];
    const int t = threadIdx.x, w = t >> 6, L = t & 63;
    const int lane15 = L & 15, quad = L >> 4;
    const int bm = blockIdx.x * 128, bn = blockIdx.y * 128;   // flipped: row-tiles fastest
    const int gr = t >> 2, ch = (t & 3) * 8;
    short* AHw = &AH[0][0] + w * 512;
    short* ALw = &AL[0][0] + w * 512;
    short* BHw = &BH[0][0] + w * 512;
    short* BLw = &BL[0][0] + w * 512;
    f32x4 acc[2][8] = {};
    for (int k0 = 0; k0 < 256; k0 += 32) {
        __syncthreads();
        gl2lds16(Xp + (size_t)(bm + gr) * 512      + k0 + ch,       AHw);
        gl2lds16(Xp + (size_t)(bm + 64 + gr) * 512 + k0 + ch,       AHw + 64 * 32);
        gl2lds16(Xp + (size_t)(bm + gr) * 512      + 256 + k0 + ch, ALw);
        gl2lds16(Xp + (size_t)(bm + 64 + gr) * 512 + 256 + k0 + ch, ALw + 64 * 32);
        gl2lds16(Wt + (size_t)(bn + gr) * 512      + k0 + ch,       BHw);
        gl2lds16(Wt + (size_t)(bn + 64 + gr) * 512 + k0 + ch,       BHw + 64 * 32);
        gl2lds16(Wt + (size_t)(bn + gr) * 512      + 256 + k0 + ch, BLw);
        gl2lds16(Wt + (size_t)(bn + 64 + gr) * 512 + 256 + k0 + ch, BLw + 64 * 32);
        __syncthreads();
        bf16x8 ah[2], al[2];
#pragma unroll
        for (int tr = 0; tr < 2; tr++) {
            ah[tr] = *(const bf16x8*)&AH[w * 32 + tr * 16 + lane15][quad * 8];
            al[tr] = *(const bf16x8*)&AL[w * 32 + tr * 16 + lane15][quad * 8];
        }
#pragma unroll
        for (int tc = 0; tc < 8; tc++) {
            const bf16x8 bh = *(const bf16x8*)&BH[tc * 16 + lane15][quad * 8];
            acc[0][tc] = __builtin_amdgcn_mfma_f32_16x16x32_bf16(ah[0], bh, acc[0][tc], 0, 0, 0);
            acc[1][tc] = __builtin_amdgcn_mfma_f32_16x16x32_bf16(ah[1], bh, acc[1][tc], 0, 0, 0);
            acc[0][tc] = __builtin_amdgcn_mfma_f32_16x16x32_bf16(al[0], bh, acc[0][tc], 0, 0, 0);
            acc[1][tc] = __builtin_amdgcn_mfma_f32_16x16x32_bf16(al[1], bh, acc[1][tc], 0, 0, 0);
            const bf16x8 bl = *(const bf16x8*)&BL[tc * 16 + lane15][quad * 8];
            acc[0][tc] = __builtin_amdgcn_mfma_f32_16x16x32_bf16(ah[0], bl, acc[0][tc], 0, 0, 0);
            acc[1][tc] = __builtin_amdgcn_mfma_f32_16x16x32_bf16(ah[1], bl, acc[1][tc], 0, 0, 0);
        }
    }
    // epilogue: per d-half, scatter (m, d) tile to LDS then write 256B-contiguous rows
#pragma unroll
    for (int h = 0; h < 2; h++) {
        __syncthreads();
#pragma unroll
        for (int tr = 0; tr < 2; tr++)
#pragma unroll
            for (int tc = 0; tc < 4; tc++) {
                const int tcg = h * 4 + tc;
                const int d = bn + tcg * 16 + lane15;
                const float bpd = bp[d];
                const float fq = freq[d] * PI_F;
#pragma unroll
                for (int r = 0; r < 4; r++) {
                    const int m = w * 32 + tr * 16 + quad * 4 + r;   // block-local row
                    const int p = (bm + m) & 255;
                    const float mg = tanhf(acc[tr][tcg][r] + bpd);
                    float sph, cph; sincosf((float)p * fq, &sph, &cph);
                    TBr[m][tc * 16 + lane15] = mg * cph;
                    TBi[m][tc * 16 + lane15] = mg * sph;
                }
            }
        __syncthreads();
#pragma unroll
        for (int g = 0; g < 8; g++) {
            const int row = (t >> 4) + g * 16;
            const int col = (t & 15) * 4;
            const float4 vr = *(const float4*)&TBr[row][col];
            const float4 vi = *(const float4*)&TBi[row][col];
            *(float4*)(Sr + (size_t)(bm + row) * DD + bn + h * 64 + col) = vr;
            *(float4*)(Si + (size_t)(bm + row) * DD + bn + h * 64 + col) = vi;
        }
    }
}

// ---------------- X/Y pack (fallback when norm can't persist X/Y) ---------------- (R12-proven)
__global__ __launch_bounds__(256) void k_xy(const float* __restrict__ Sr, const float* __restrict__ Si,
        const float* __restrict__ cd, const float* __restrict__ sd,
        unsigned short* X, unsigned short* Y,
        const int* __restrict__ active) {
    if (*active == 0) return;
    const int r = blockIdx.x, t = threadIdx.x;
    const size_t base = (size_t)r * DD + 2 * t;
    const float2 s_r = *(const float2*)(Sr + base);
    const float2 s_i = *(const float2*)(Si + base);
    const float2 c2  = *(const float2*)(cd + 2 * t);
    const float2 s2  = *(const float2*)(sd + 2 * t);
    unsigned short* xr = X + (size_t)r * KA;
    unsigned short* yr = Y + (size_t)r * KA;
    const float srv[2] = {s_r.x, s_r.y}, siv[2] = {s_i.x, s_i.y};
    const float cv_[2] = {c2.x, c2.y},  sv_[2] = {s2.x, s2.y};
    ushort2 xh_r, xh_i, xl_r, xl_i, yh_r, yh_i, yl_r, yl_i;
    unsigned short* o[8] = {(unsigned short*)&xh_r, (unsigned short*)&xh_i,
                            (unsigned short*)&xl_r, (unsigned short*)&xl_i,
                            (unsigned short*)&yh_r, (unsigned short*)&yh_i,
                            (unsigned short*)&yl_r, (unsigned short*)&yl_i};
#pragma unroll
    for (int e = 0; e < 2; e++) {
        const unsigned short hr = f2bf(srv[e]);
        const unsigned short hi_ = f2bf(siv[e]);
        o[0][e] = hr;  o[2][e] = f2bf(srv[e] - bf2f(hr));
        o[1][e] = hi_; o[3][e] = f2bf(siv[e] - bf2f(hi_));
        const float krr = srv[e] * cv_[e] + siv[e] * sv_[e];
        const float kri = siv[e] * cv_[e] - srv[e] * sv_[e];
        const unsigned short yh1 = f2bf(krr);
        const unsigned short yh2 = f2bf(kri);
        o[4][e] = yh1; o[6][e] = f2bf(krr - bf2f(yh1));
        o[5][e] = yh2; o[7][e] = f2bf(kri - bf2f(yh2));
    }
    *(ushort2*)(xr + 2 * t)        = xh_r;
    *(ushort2*)(xr + 512 + 2 * t)  = xh_i;
    *(ushort2*)(xr + 1024 + 2 * t) = xl_r;
    *(ushort2*)(xr + 1536 + 2 * t) = xl_i;
    *(ushort2*)(yr + 2 * t)        = yh_r;
    *(ushort2*)(yr + 512 + 2 * t)  = yh_i;
    *(ushort2*)(yr + 1024 + 2 * t) = yl_r;
    *(ushort2*)(yr + 1536 + 2 * t) = yl_i;
}

// ---------------- fused score+softmax: S=scale*(X@Y^T) 3-term, row softmax, bf16-split out ----------------
// M-tile 64 x full 256 q. R3: XCD co-location — the 4 row-tiles of a sample have ids s, s+C, s+2C, s+3C
// (C multiple of 8 -> same XCD -> per-phase Y slices L2-hot).
__global__ __launch_bounds__(256) void k_score_sm(const unsigned short* __restrict__ X,
        const unsigned short* __restrict__ Y,
        unsigned short* __restrict__ Asp, const int* __restrict__ active) {
    if (*active == 0) return;
    __shared__ short XH[64][32], XL[64][32];
    __shared__ short YH[256][32], YL[256][32];
    const int t = threadIdx.x;
    const int w = t >> 6, L = t & 63;
    const int lane15 = L & 15, quad = L >> 4;
    const int nsm = (int)gridDim.x >> 2;           // C (power of 2)
    const int s   = (int)blockIdx.x & (nsm - 1);   // chunk-local sample
    const int rt  = (int)blockIdx.x / nsm;         // row-tile 0..3
    const int bm = s * 256 + rt * 64;              // chunk-local row base
    const int yb = s * 256;                        // sample's Y rows
    const int gr = t >> 2, ch = (t & 3) * 8;
    short* XHw = &XH[0][0] + w * 512;
    short* XLw = &XL[0][0] + w * 512;
    short* YHw = &YH[0][0] + w * 512;
    short* YLw = &YL[0][0] + w * 512;
    f32x4 acc[16] = {};
    for (int k0 = 0; k0 < 1024; k0 += 32) {
        __syncthreads();
        gl2lds16(X + (size_t)(bm + gr) * KA + k0 + ch,        XHw);
        gl2lds16(X + (size_t)(bm + gr) * KA + 1024 + k0 + ch, XLw);
#pragma unroll
        for (int ss = 0; ss < 4; ss++) {
            gl2lds16(Y + (size_t)(yb + ss * 64 + gr) * KA + k0 + ch,        YHw + ss * 2048);
            gl2lds16(Y + (size_t)(yb + ss * 64 + gr) * KA + 1024 + k0 + ch, YLw + ss * 2048);
        }
        __syncthreads();
        const bf16x8 xh = *(const bf16x8*)&XH[w * 16 + lane15][quad * 8];
        const bf16x8 xl = *(const bf16x8*)&XL[w * 16 + lane15][quad * 8];
#pragma unroll
        for (int tc = 0; tc < 16; tc++) {
            const bf16x8 yh = *(const bf16x8*)&YH[tc * 16 + lane15][quad * 8];
            acc[tc] = __builtin_amdgcn_mfma_f32_16x16x32_bf16(xh, yh, acc[tc], 0, 0, 0);
            acc[tc] = __builtin_amdgcn_mfma_f32_16x16x32_bf16(xl, yh, acc[tc], 0, 0, 0);
            const bf16x8 yl = *(const bf16x8*)&YL[tc * 16 + lane15][quad * 8];
            acc[tc] = __builtin_amdgcn_mfma_f32_16x16x32_bf16(xh, yl, acc[tc], 0, 0, 0);
        }
    }
    // softmax epilogue: row = bm + w*16 + quad*4 + r; q = tc*16 + lane15
#pragma unroll
    for (int tc = 0; tc < 16; tc++) acc[tc] *= SCALE_F;
#pragma unroll
    for (int r = 0; r < 4; r++) {
        float mx = acc[0][r];
#pragma unroll
        for (int tc = 1; tc < 16; tc++) mx = fmaxf(mx, acc[tc][r]);
#pragma unroll
        for (int off = 8; off; off >>= 1) mx = fmaxf(mx, __shfl_xor(mx, off, 64));
        float sum = 0.f;
        float e[16];
#pragma unroll
        for (int tc = 0; tc < 16; tc++) { e[tc] = __expf(acc[tc][r] - mx); sum += e[tc]; }
#pragma unroll
        for (int off = 8; off; off >>= 1) sum += __shfl_xor(sum, off, 64);
        const float inv = 1.0f / sum;
        const int row = bm + w * 16 + quad * 4 + r;
        unsigned short* o = Asp + (size_t)row * 512;
#pragma unroll
        for (int tc = 0; tc < 16; tc++) {
            const float p = e[tc] * inv;
            const unsigned short h = f2bf(p);
            o[tc * 16 + lane15] = h;
            o[256 + tc * 16 + lane15] = f2bf(p - bf2f(h));
        }
    }
}

// ---------------- attn_out via split-bf16 MFMA (3-term), fused v-rot + prev-add epilogue ----------------
// R3: grid flipped (x = row-tile, y = d-tile): the 8 d-blocks sharing one Asp tile differ by C*2
// block ids -> same XCD -> staged A slices L2-hot.
__global__ __launch_bounds__(256) void k_attnout_mfma(const unsigned short* __restrict__ Asp,
        const unsigned short* __restrict__ X,
        const float* __restrict__ Sr, const float* __restrict__ Si,
        const float* __restrict__ cv, const float* __restrict__ sv,
        unsigned short* __restrict__ A2, const int* __restrict__ active) {
    if (*active == 0) return;
    __shared__ short AhT[128][32];
    __shared__ short AlT[128][32];
    __shared__ short BH[128][40];   // +8 pad: 80B row stride -> b128 r/w at the bank floor
    __shared__ short BL[128][40];
    const int t = threadIdx.x;
    const int w = t >> 6, L = t & 63;
    const int lane15 = L & 15, quad = L >> 4;
    const int bm = blockIdx.x * 128;          // chunk-local row base (flipped)
    const int bn = blockIdx.y * 64;           // d base (0..448)
    const int sample = blockIdx.x >> 1;       // chunk-local sample
    const int gr = t >> 2, ch = (t & 3) * 8;
    short* AhW0 = &AhT[0][0] + w * 512;
    short* AhW1 = AhW0 + 64 * 32;
    short* AlW0 = &AlT[0][0] + w * 512;
    short* AlW1 = AlW0 + 64 * 32;
    const int nn = t & 127, kh = t >> 7;
    const unsigned short* Bsrc = X + (size_t)sample * PP * KA
                               + ((nn < 64) ? (bn + nn) : (512 + bn + nn - 64));
    f32x4 acc[2][8] = {};
    for (int q0 = 0; q0 < PP; q0 += 32) {
        __syncthreads();
        gl2lds16(Asp + (size_t)(bm + gr) * 512      + q0 + ch,       AhW0);
        gl2lds16(Asp + (size_t)(bm + 64 + gr) * 512 + q0 + ch,       AhW1);
        gl2lds16(Asp + (size_t)(bm + gr) * 512      + 256 + q0 + ch, AlW0);
        gl2lds16(Asp + (size_t)(bm + 64 + gr) * 512 + 256 + q0 + ch, AlW1);
#pragma unroll
        for (int kg = 0; kg < 2; kg++) {
            const int qb = kh * 16 + kg * 8;
            bf16x8 hh, ll;
#pragma unroll
            for (int j = 0; j < 8; j++) {
                const size_t o = (size_t)(q0 + qb + j) * KA;
                hh[j] = (short)Bsrc[o];
                ll[j] = (short)Bsrc[o + 1024];
            }
            *(bf16x8*)&BH[nn][qb] = hh;
            *(bf16x8*)&BL[nn][qb] = ll;
        }
        __syncthreads();
        bf16x8 bh[8];
#pragma unroll
        for (int tc = 0; tc < 8; tc++)
            bh[tc] = *(const bf16x8*)&BH[tc * 16 + lane15][quad * 8];
        bf16x8 afh[2];
#pragma unroll
        for (int tr = 0; tr < 2; tr++) {
            afh[tr] = *(const bf16x8*)&AhT[w * 32 + tr * 16 + lane15][quad * 8];
            const bf16x8 afl = *(const bf16x8*)&AlT[w * 32 + tr * 16 + lane15][quad * 8];
#pragma unroll
            for (int tc = 0; tc < 8; tc++)
                acc[tr][tc] = __builtin_amdgcn_mfma_f32_16x16x32_bf16(afh[tr], bh[tc], acc[tr][tc], 0, 0, 0);
#pragma unroll
            for (int tc = 0; tc < 8; tc++)
                acc[tr][tc] = __builtin_amdgcn_mfma_f32_16x16x32_bf16(afl, bh[tc], acc[tr][tc], 0, 0, 0);
        }
#pragma unroll
        for (int tc = 0; tc < 8; tc++) {
            const bf16x8 bl = *(const bf16x8*)&BL[tc * 16 + lane15][quad * 8];
            acc[0][tc] = __builtin_amdgcn_mfma_f32_16x16x32_bf16(afh[0], bl, acc[0][tc], 0, 0, 0);
            acc[1][tc] = __builtin_amdgcn_mfma_f32_16x16x32_bf16(afh[1], bl, acc[1][tc], 0, 0, 0);
        }
    }
#pragma unroll
    for (int tr = 0; tr < 2; tr++) {
#pragma unroll
        for (int tc = 0; tc < 4; tc++) {
            const int d = bn + tc * 16 + lane15;
            const float cvd = cv[d], svd = sv[d];
#pragma unroll
            for (int r = 0; r < 4; r++) {
                const int m = bm + w * 32 + tr * 16 + quad * 4 + r;  // chunk-local row
                const float wr = acc[tr][tc][r];
                const float wi = acc[tr][tc + 4][r];
                const float tr_ = Sr[(size_t)m * DD + d] + (wr * cvd - wi * svd);
                const float ti_ = Si[(size_t)m * DD + d] + (wr * svd + wi * cvd);
                const unsigned short rh = f2bf(tr_);
                const unsigned short ih = f2bf(ti_);
                unsigned short* arow = A2 + (size_t)m * KA;
                arow[d]        = rh;
                arow[512 + d]  = ih;
                arow[1024 + d] = f2bf(tr_ - bf2f(rh));
                arow[1536 + d] = f2bf(ti_ - bf2f(ih));
            }
        }
    }
}

// ---------------- ff via split-bf16 MFMA, 48-MFMA phases, Bt2=[hi|lo] ----------------
// R3: grid flipped (x = row-tile, y = n-tile): the 8 n-blocks sharing one A2 tile differ by C*2
// block ids -> same XCD.
__global__ __launch_bounds__(256) void k_ff_mfma2(const unsigned short* __restrict__ A2,
        const unsigned short* __restrict__ Bt2,
        float* __restrict__ U, const int* __restrict__ active) {
    if (*active == 0) return;
    __shared__ short AH[128][32], AL[128][32];
    __shared__ short BH[128][32], BL[128][32];
    const int t = threadIdx.x;
    const int w = t >> 6, L = t & 63;
    const int lane15 = L & 15, quad = L >> 4;
    const int bm = blockIdx.x * 128, bn = blockIdx.y * 128;   // flipped
    const int gr = t >> 2, ch = (t & 3) * 8;
    short* AHw = &AH[0][0] + w * 512;
    short* ALw = &AL[0][0] + w * 512;
    short* BHw = &BH[0][0] + w * 512;
    short* BLw = &BL[0][0] + w * 512;
    f32x4 acc[2][8] = {};
    for (int k0 = 0; k0 < 1024; k0 += 32) {
        __syncthreads();
        gl2lds16(A2  + (size_t)(bm + gr) * KA       + k0 + ch,        AHw);
        gl2lds16(A2  + (size_t)(bm + 64 + gr) * KA  + k0 + ch,        AHw + 64 * 32);
        gl2lds16(A2  + (size_t)(bm + gr) * KA       + 1024 + k0 + ch, ALw);
        gl2lds16(A2  + (size_t)(bm + 64 + gr) * KA  + 1024 + k0 + ch, ALw + 64 * 32);
        gl2lds16(Bt2 + (size_t)(bn + gr) * KB2      + k0 + ch,        BHw);
        gl2lds16(Bt2 + (size_t)(bn + 64 + gr) * KB2 + k0 + ch,        BHw + 64 * 32);
        gl2lds16(Bt2 + (size_t)(bn + gr) * KB2      + 1024 + k0 + ch, BLw);
        gl2lds16(Bt2 + (size_t)(bn + 64 + gr) * KB2 + 1024 + k0 + ch, BLw + 64 * 32);
        __syncthreads();
        bf16x8 ah[2], al[2];
#pragma unroll
        for (int tr = 0; tr < 2; tr++) {
            ah[tr] = *(const bf16x8*)&AH[w * 32 + tr * 16 + lane15][quad * 8];
            al[tr] = *(const bf16x8*)&AL[w * 32 + tr * 16 + lane15][quad * 8];
        }
#pragma unroll
        for (int tc = 0; tc < 8; tc++) {
            const bf16x8 bh = *(const bf16x8*)&BH[tc * 16 + lane15][quad * 8];
            acc[0][tc] = __builtin_amdgcn_mfma_f32_16x16x32_bf16(ah[0], bh, acc[0][tc], 0, 0, 0);
            acc[1][tc] = __builtin_amdgcn_mfma_f32_16x16x32_bf16(ah[1], bh, acc[1][tc], 0, 0, 0);
            acc[0][tc] = __builtin_amdgcn_mfma_f32_16x16x32_bf16(al[0], bh, acc[0][tc], 0, 0, 0);
            acc[1][tc] = __builtin_amdgcn_mfma_f32_16x16x32_bf16(al[1], bh, acc[1][tc], 0, 0, 0);
            const bf16x8 bl = *(const bf16x8*)&BL[tc * 16 + lane15][quad * 8];
            acc[0][tc] = __builtin_amdgcn_mfma_f32_16x16x32_bf16(ah[0], bl, acc[0][tc], 0, 0, 0);
            acc[1][tc] = __builtin_amdgcn_mfma_f32_16x16x32_bf16(ah[1], bl, acc[1][tc], 0, 0, 0);
        }
    }
#pragma unroll
    for (int tr = 0; tr < 2; tr++)
#pragma unroll
        for (int tc = 0; tc < 8; tc++) {
            const int n = bn + tc * 16 + lane15;
            const int mbase = bm + w * 32 + tr * 16 + quad * 4;
#pragma unroll
            for (int r = 0; r < 4; r++)
                U[(size_t)(mbase + r) * NK + n] = acc[tr][tc][r];
        }
}

// ---------------- complex_norm + commit + partial + fused X/Y pack ----------------
// NOTE: X overlays U byte-exactly per row; every X store data-depends on all U loads
// (via the cross-lane mean/var reduction), so in-place is safe. No __restrict__ on U/X/Y.
__global__ __launch_bounds__(256) void k_norm(const float* U,
        float* __restrict__ Sr, float* __restrict__ Si,
        float* __restrict__ part,
        unsigned short* X, unsigned short* Y,
        const float* __restrict__ cd, const float* __restrict__ sd,
        const int wxy, const int* __restrict__ active) {
    if (*active == 0) return;
    __shared__ float red[8];
    const int t = threadIdx.x, rt = t >> 6, L = t & 63;
    const int row = blockIdx.x * 4 + rt;
    const size_t ub = (size_t)row * NK;
    const size_t base = (size_t)row * DD;
    const float4 ur0 = *(const float4*)(U + ub + 4 * L);
    const float4 ur1 = *(const float4*)(U + ub + 256 + 4 * L);
    const float4 ui0 = *(const float4*)(U + ub + 512 + 4 * L);
    const float4 ui1 = *(const float4*)(U + ub + 768 + 4 * L);
    const float4 pr0 = *(const float4*)(Sr + base + 4 * L);
    const float4 pr1 = *(const float4*)(Sr + base + 256 + 4 * L);
    const float4 pi0 = *(const float4*)(Si + base + 4 * L);
    const float4 pi1 = *(const float4*)(Si + base + 256 + 4 * L);
    const float urr[8] = {ur0.x, ur0.y, ur0.z, ur0.w, ur1.x, ur1.y, ur1.z, ur1.w};
    const float uii[8] = {ui0.x, ui0.y, ui0.z, ui0.w, ui1.x, ui1.y, ui1.z, ui1.w};
    float mg[8], msum = 0.f;
#pragma unroll
    for (int e = 0; e < 8; e++) {
        mg[e] = sqrtf(urr[e] * urr[e] + uii[e] * uii[e]);
        msum += mg[e];
    }
#pragma unroll
    for (int off = 32; off; off >>= 1) msum += __shfl_xor(msum, off, 64);
    const float mean = msum * (1.0f / 512.0f);
    float vs = 0.f;
#pragma unroll
    for (int e = 0; e < 8; e++) { const float d = mg[e] - mean; vs += d * d; }
#pragma unroll
    for (int off = 32; off; off >>= 1) vs += __shfl_xor(vs, off, 64);
    const float istd = 1.0f / (sqrtf(vs * (1.0f / 511.0f)) + 1e-5f);
    float nr[8], ni[8];
#pragma unroll
    for (int e = 0; e < 8; e++) {
        const float sc = tanhf((mg[e] - mean) * istd) / (mg[e] + 1e-5f);
        nr[e] = urr[e] * sc; ni[e] = uii[e] * sc;
    }
    const float prr[8] = {pr0.x, pr0.y, pr0.z, pr0.w, pr1.x, pr1.y, pr1.z, pr1.w};
    const float pii[8] = {pi0.x, pi0.y, pi0.z, pi0.w, pi1.x, pi1.y, pi1.z, pi1.w};
    float dd = 0.f, nn = 0.f;
#pragma unroll
    for (int e = 0; e < 8; e++) {
        const float dr = nr[e] - prr[e], di = ni[e] - pii[e];
        dd += dr * dr + di * di;
        nn += nr[e] * nr[e] + ni[e] * ni[e];
    }
    *(float4*)(Sr + base + 4 * L)       = make_float4(nr[0], nr[1], nr[2], nr[3]);
    *(float4*)(Sr + base + 256 + 4 * L) = make_float4(nr[4], nr[5], nr[6], nr[7]);
    *(float4*)(Si + base + 4 * L)       = make_float4(ni[0], ni[1], ni[2], ni[3]);
    *(float4*)(Si + base + 256 + 4 * L) = make_float4(ni[4], ni[5], ni[6], ni[7]);
    if (wxy) {
        unsigned short* xr = X + (size_t)row * KA;
        unsigned short* yr = Y + (size_t)row * KA;
        const float4 c0 = *(const float4*)(cd + 4 * L);
        const float4 c1 = *(const float4*)(cd + 256 + 4 * L);
        const float4 s0 = *(const float4*)(sd + 4 * L);
        const float4 s1 = *(const float4*)(sd + 256 + 4 * L);
        const float cdv[8] = {c0.x, c0.y, c0.z, c0.w, c1.x, c1.y, c1.z, c1.w};
        const float sdv[8] = {s0.x, s0.y, s0.z, s0.w, s1.x, s1.y, s1.z, s1.w};
        ushort4 xhr[2], xhi[2], xlr[2], xli[2], yhr[2], yhi[2], ylr[2], yli[2];
#pragma unroll
        for (int e = 0; e < 8; e++) {
            const int g = e >> 2, j = e & 3;
            const unsigned short hr = f2bf(nr[e]);
            const unsigned short hi_ = f2bf(ni[e]);
            ((unsigned short*)&xhr[g])[j] = hr;
            ((unsigned short*)&xlr[g])[j] = f2bf(nr[e] - bf2f(hr));
            ((unsigned short*)&xhi[g])[j] = hi_;
            ((unsigned short*)&xli[g])[j] = f2bf(ni[e] - bf2f(hi_));
            const float krr = nr[e] * cdv[e] + ni[e] * sdv[e];
            const float kri = ni[e] * cdv[e] - nr[e] * sdv[e];
            const unsigned short k1 = f2bf(krr);
            const unsigned short k2 = f2bf(kri);
            ((unsigned short*)&yhr[g])[j] = k1;
            ((unsigned short*)&ylr[g])[j] = f2bf(krr - bf2f(k1));
            ((unsigned short*)&yhi[g])[j] = k2;
            ((unsigned short*)&yli[g])[j] = f2bf(kri - bf2f(k2));
        }
        *(ushort4*)(xr + 4 * L)        = xhr[0]; *(ushort4*)(xr + 256 + 4 * L)  = xhr[1];
        *(ushort4*)(xr + 512 + 4 * L)  = xhi[0]; *(ushort4*)(xr + 768 + 4 * L)  = xhi[1];
        *(ushort4*)(xr + 1024 + 4 * L) = xlr[0]; *(ushort4*)(xr + 1280 + 4 * L) = xlr[1];
        *(ushort4*)(xr + 1536 + 4 * L) = xli[0]; *(ushort4*)(xr + 1792 + 4 * L) = xli[1];
        *(ushort4*)(yr + 4 * L)        = yhr[0]; *(ushort4*)(yr + 256 + 4 * L)  = yhr[1];
        *(ushort4*)(yr + 512 + 4 * L)  = yhi[0]; *(ushort4*)(yr + 768 + 4 * L)  = yhi[1];
        *(ushort4*)(yr + 1024 + 4 * L) = ylr[0]; *(ushort4*)(yr + 1280 + 4 * L) = ylr[1];
        *(ushort4*)(yr + 1536 + 4 * L) = yli[0]; *(ushort4*)(yr + 1792 + 4 * L) = yli[1];
    }
#pragma unroll
    for (int off = 32; off; off >>= 1) {
        dd += __shfl_xor(dd, off, 64);
        nn += __shfl_xor(nn, off, 64);
    }
    if (L == 0) { red[rt] = dd; red[4 + rt] = nn; }
    __syncthreads();
    if (t == 0)
        *(float2*)(part + 2 * blockIdx.x) =
            make_float2(red[0] + red[1] + red[2] + red[3],
                        red[4] + red[5] + red[6] + red[7]);
}

// ---------------- convergence flag: reduce all NSLOT partials ----------------
__global__ __launch_bounds__(256) void k_flag(const float* __restrict__ part, int* __restrict__ active) {
    __shared__ float red[8];
    const int t = threadIdx.x, rt = t >> 6, L = t & 63;
    float dd = 0.f, nn = 0.f;
    for (int i = t; i < NSLOT; i += 256) {
        const float2 p = *(const float2*)(part + 2 * i);
        dd += p.x; nn += p.y;
    }
#pragma unroll
    for (int off = 32; off; off >>= 1) {
        dd += __shfl_xor(dd, off, 64);
        nn += __shfl_xor(nn, off, 64);
    }
    if (L == 0) { red[rt] = dd; red[4 + rt] = nn; }
    __syncthreads();
    if (t == 0) {
        const float d = red[0] + red[1] + red[2] + red[3];
        const float n = red[4] + red[5] + red[6] + red[7];
        const float diff = sqrtf(d) / (sqrtf(n) + 1e-8f);
        const int a = *active;
        *active = (a && (diff >= 1e-3f)) ? 1 : 0;
    }
}

// ---------------- mean over P ----------------
__global__ __launch_bounds__(256) void k_pool(const float* __restrict__ Sr, const float* __restrict__ Si,
        float* __restrict__ Pr, float* __restrict__ Pi) {
    const int gid = blockIdx.x * 256 + threadIdx.x;
    const int b = gid >> 9, d = gid & 511;
    const size_t base = (size_t)b * PP * DD + d;
    float sr = 0.f, si = 0.f;
    for (int p = 0; p < PP; p++) {
        sr += Sr[base + (size_t)p * DD];
        si += Si[base + (size_t)p * DD];
    }
    Pr[gid] = sr * (1.0f / 256.0f);
    Pi[gid] = si * (1.0f / 256.0f);
}

// ---------------- logits ----------------
__global__ __launch_bounds__(64) void k_logits(const float* __restrict__ Pr, const float* __restrict__ Pi,
        const float* __restrict__ Wr, const float* __restrict__ br,
        const float* __restrict__ Wi, const float* __restrict__ bi,
        float* __restrict__ out) {
    const int b = blockIdx.x;
    const int lane = threadIdx.x;
    for (int c = 0; c < CC; c++) {
        float acc = 0.f;
#pragma unroll
        for (int k = 0; k < 8; k++) {
            const int d = lane + 64 * k;
            acc += Pr[b * DD + d] * Wr[c * DD + d] + Pi[b * DD + d] * Wi[c * DD + d];
        }
#pragma unroll
        for (int off = 32; off; off >>= 1) acc += __shfl_xor(acc, off, 64);
        if (lane == 0) out[b * CC + c] = acc + br[c] + bi[c];
    }
}

extern "C" void kernel_launch(void* const* d_in, const int* in_sizes, int n_in,
                              void* d_out, int out_size, void* d_ws, size_t ws_size,
                              hipStream_t stream) {
    const float* x     = (const float*)d_in[0];
    const float* Wp    = (const float*)d_in[1];
    const float* bp    = (const float*)d_in[2];
    const float* q_rot = (const float*)d_in[3];
    const float* k_rot = (const float*)d_in[4];
    const float* v_rot = (const float*)d_in[5];
    const float* ffr   = (const float*)d_in[6];
    const float* ffi   = (const float*)d_in[7];
    const float* Wr    = (const float*)d_in[8];
    const float* br    = (const float*)d_in[9];
    const float* Wi    = (const float*)d_in[10];
    const float* bi    = (const float*)d_in[11];
    float* out = (float*)d_out;

    float* ws = (float*)d_ws;
    const size_t plane = (size_t)MTOT * DD;      // 16,777,216 floats
    const size_t sline = (size_t)PP * DD;

    float* freq = ws;                  // 512
    float* cd   = freq + DD;
    float* sd   = cd + DD;
    float* cv   = sd + DD;
    float* sv   = cv + DD;
    int*   active = (int*)(sv + DD);   // 1
    float* Pr = ws + 4096;             // 65536
    float* Pi = Pr + (size_t)BB * DD;  // 65536
    float* part = Pi + (size_t)BB * DD;        // 2*NSLOT = 16384 floats
    float* Sr = part + 2 * NSLOT;              // fp32 state (128 MiB)
    float* Si = Sr + plane;
    unsigned short* Bt2 = (unsigned short*)(Si + plane);   // 1024x2048 bf16 (4 MB)
    unsigned short* Wt  = Bt2 + (size_t)NK * KB2;          // 512x512 bf16 (0.5 MB), inside 6MB hole
    float* chunkbase = Si + plane + (size_t)NK * 3072 / 2; // 6MB hole reserved (Bt2 + Wt fit)

    const size_t fixed_f = (4096 + 2 * (size_t)BB * DD + 2 * NSLOT) + 2 * plane + (size_t)NK * 3072 / 2;
    // per-sample: X/U overlay (1 MB) + Y/A2 overlay (1 MB) + Asp (256 KB) = 2.25 MB
    const size_t perC_f = (size_t)PP * NK * 2 + (size_t)PP * 256;   // 589824 floats

    int C = BB;
    while (C > 1 && (fixed_f + (size_t)C * perC_f) * 4ull > ws_size) C >>= 1;
    const int fullXY = (C == BB);      // X/Y persist across iterations -> norm packs them
    const int mfmaInit = (C >= 32);    // Xp (67 MB) fits in the chunk region

    float* U = chunkbase;                                       // C x 256 x 1024 fp32
    unsigned short* X  = (unsigned short*)chunkbase;            // overlay: X dead before ff writes U
    float* Yf = chunkbase + (size_t)C * PP * NK;
    unsigned short* Y  = (unsigned short*)Yf;                   // C x 256 x 2048 bf16
    unsigned short* A2 = Y;                                     // overlay: Y dead after k_score_sm
    unsigned short* Asp = (unsigned short*)(Yf + (size_t)C * PP * NK);  // C x 256 x 512 bf16
    unsigned short* Xp = (unsigned short*)chunkbase;            // init staging overlay (dead pre-loop)

    k_setup<<<1, 512, 0, stream>>>(q_rot, k_rot, v_rot, freq, cd, sd, cv, sv, active);
    k_prep2<<<NK, 256, 0, stream>>>(ffr, ffi, Bt2);
    if (mfmaInit) {
        k_packx<<<MTOT, 256, 0, stream>>>(x, Xp);
        k_wpack<<<DD, 256, 0, stream>>>(Wp, Wt);
        k_init_mfma<<<dim3(MTOT / 128, DD / 128), 256, 0, stream>>>(Xp, Wt, bp, freq, Sr, Si);
    } else {
        k_init<<<dim3(DD / 64, MTOT / 64), 256, 0, stream>>>(x, Wp, bp, freq, Sr, Si);
    }

    for (int it = 0; it < 4; ++it) {
        for (int c0 = 0; c0 < BB; c0 += C) {
            float* Sr_c = Sr + (size_t)c0 * sline;
            float* Si_c = Si + (size_t)c0 * sline;
            float* part_c = part + (size_t)c0 * (PP / 4) * 2;
            if (!fullXY || it == 0)
                k_xy<<<C * PP, 256, 0, stream>>>(Sr_c, Si_c, cd, sd, X, Y, active);
            k_score_sm<<<C * 4, 256, 0, stream>>>(X, Y, Asp, active);
            k_attnout_mfma<<<dim3(C * 2, 8), 256, 0, stream>>>(Asp, X, Sr_c, Si_c, cv, sv, A2, active);
            k_ff_mfma2<<<dim3(C * 2, NK / 128), 256, 0, stream>>>(A2, Bt2, U, active);
            k_norm<<<C * (PP / 4), 256, 0, stream>>>(U, Sr_c, Si_c, part_c, X, Y, cd, sd, fullXY, active);
        }
        k_flag<<<1, 256, 0, stream>>>(part, active);
    }

    k_pool<<<BB * DD / 256, 256, 0, stream>>>(Sr, Si, Pr, Pi);
    k_logits<<<BB, 64, 0, stream>>>(Pr, Pi, Wr, br, Wi, bi, out);
}

// Round 4
// 3007.714 us; speedup vs baseline: 1.3898x; 1.0387x over previous
//
#include <hip/hip_runtime.h>
#include <math.h>

#define BB   128
#define PP   256
#define PIX_ 256
#define DD   512
#define CC   10
#define MTOT (BB*PP)   // 32768
#define NK   1024      // packed complex N for the ff GEMM
#define KA   2048      // A2 / X / Y row length (hi|lo)
#define KB2  2048      // Bt2 row length (hi|lo)
#define NSLOT (MTOT/4) // 8192 partial slots (one per norm block, whole batch)

static constexpr float SCALE_F = 0.35355339059327373f; // 8/sqrt(512)
static constexpr float PI_F    = 3.14159265358979323846f;

typedef short bf16x8 __attribute__((ext_vector_type(8)));
typedef float f32x4  __attribute__((ext_vector_type(4)));

__device__ __forceinline__ unsigned short f2bf(float f) {
    union { float f; unsigned u; } v; v.f = f;
    unsigned r = v.u + 0x7FFF + ((v.u >> 16) & 1);   // RNE
    return (unsigned short)(r >> 16);
}
__device__ __forceinline__ float bf2f(unsigned short h) {
    union { unsigned u; float f; } v; v.u = ((unsigned)h) << 16;
    return v.f;
}

// async global->LDS, 16B per lane; LDS dest = wave-uniform base + lane*16B (m97 pattern)
typedef __attribute__((address_space(3))) unsigned lds_u32;
typedef __attribute__((address_space(1))) const unsigned glb_u32;
__device__ __forceinline__ void gl2lds16(const unsigned short* g, short* l) {
    __builtin_amdgcn_global_load_lds((glb_u32*)g, (lds_u32*)l, 16, 0, 0);
}

// ---------------- setup ----------------
__global__ void k_setup(const float* __restrict__ q_rot, const float* __restrict__ k_rot,
                        const float* __restrict__ v_rot,
                        float* __restrict__ freq, float* __restrict__ cd, float* __restrict__ sd,
                        float* __restrict__ cv, float* __restrict__ sv,
                        int* __restrict__ active) {
    int t = threadIdx.x;
    if (t < DD) {
        freq[t] = expf(-(float)t * (9.210340371976184f / 512.0f)); // 10000^(-d/512)
        float dl = q_rot[t] - k_rot[t];
        cd[t] = cosf(dl);       sd[t] = sinf(dl);
        cv[t] = cosf(v_rot[t]); sv[t] = sinf(v_rot[t]);
    }
    if (t == 0) *active = 1;
}

// ---------------- build Bt2[n][0:2048] = [Bhi | Blo] (k-major) ----------------
__global__ __launch_bounds__(256) void k_prep2(const float* __restrict__ Fr, const float* __restrict__ Fi,
                                               unsigned short* __restrict__ Bt2) {
    const int n = blockIdx.x;           // 0..1023
    const int t = threadIdx.x;
    unsigned short* row = Bt2 + (size_t)n * KB2;
#pragma unroll
    for (int j4 = 0; j4 < 4; j4++) {
        const int j = j4 * 256 + t;
        float v;
        if (n < 512) v = (j < 512) ? Fr[(size_t)j * DD + n] : -Fi[(size_t)(j - 512) * DD + n];
        else         v = (j < 512) ? Fi[(size_t)j * DD + (n - 512)] : Fr[(size_t)(j - 512) * DD + (n - 512)];
        const unsigned short hi = f2bf(v);
        row[j] = hi;
        row[NK + j] = f2bf(v - bf2f(hi));
    }
}

#define SCAT4(TILE, V4) do { TILE[lk+0][lrow]=(V4).x; TILE[lk+1][lrow]=(V4).y; \
                             TILE[lk+2][lrow]=(V4).z; TILE[lk+3][lrow]=(V4).w; } while(0)

// ---------------- init: state = tanh(x@Wp^T + bp) * e^{i*p*freq*pi} ---------------- (R2-proven, 152us)
__global__ __launch_bounds__(256) void k_init(const float* __restrict__ x,
        const float* __restrict__ Wp, const float* __restrict__ bp,
        const float* __restrict__ freq,
        float* __restrict__ Sr, float* __restrict__ Si) {
    __shared__ float As[16][68];
    __shared__ float Bs[16][68];
    const int bm = blockIdx.y * 64, bn = blockIdx.x * 64;
    const int t = threadIdx.x, tx = t & 15, ty = t >> 4;
    const int lrow = t >> 2, lk = (t & 3) * 4;
    float acc[4][4] = {};
    for (int k0 = 0; k0 < PIX_; k0 += 16) {
        const float4 a4 = *(const float4*)(x  + (size_t)(bm + lrow) * PIX_ + k0 + lk);
        const float4 b4 = *(const float4*)(Wp + (size_t)(bn + lrow) * PIX_ + k0 + lk);
        __syncthreads();
        SCAT4(As, a4);
        SCAT4(Bs, b4);
        __syncthreads();
#pragma unroll
        for (int kk = 0; kk < 16; ++kk) {
            const float4 av = *(const float4*)&As[kk][ty * 4];
            const float4 bv = *(const float4*)&Bs[kk][tx * 4];
            const float a[4] = {av.x, av.y, av.z, av.w};
            const float b[4] = {bv.x, bv.y, bv.z, bv.w};
#pragma unroll
            for (int i = 0; i < 4; i++)
#pragma unroll
                for (int j = 0; j < 4; j++) acc[i][j] = fmaf(a[i], b[j], acc[i][j]);
        }
    }
#pragma unroll
    for (int i = 0; i < 4; i++) {
        const int m = bm + ty * 4 + i;
        const int p = m & 255;
        float4 vr, vi;
        float* pvr = (float*)&vr; float* pvi = (float*)&vi;
#pragma unroll
        for (int j = 0; j < 4; j++) {
            const int d = bn + tx * 4 + j;
            const float mg = tanhf(acc[i][j] + bp[d]);
            const float ph = (float)p * freq[d] * PI_F;
            float sph, cph; sincosf(ph, &sph, &cph);
            pvr[j] = mg * cph; pvi[j] = mg * sph;
        }
        *(float4*)(Sr + (size_t)m * DD + bn + tx * 4) = vr;
        *(float4*)(Si + (size_t)m * DD + bn + tx * 4) = vi;
    }
}

// ---------------- X/Y pack (fallback when norm can't persist X/Y) ---------------- (R12-proven)
__global__ __launch_bounds__(256) void k_xy(const float* __restrict__ Sr, const float* __restrict__ Si,
        const float* __restrict__ cd, const float* __restrict__ sd,
        unsigned short* X, unsigned short* Y,
        const int* __restrict__ active) {
    if (*active == 0) return;
    const int r = blockIdx.x, t = threadIdx.x;
    const size_t base = (size_t)r * DD + 2 * t;
    const float2 s_r = *(const float2*)(Sr + base);
    const float2 s_i = *(const float2*)(Si + base);
    const float2 c2  = *(const float2*)(cd + 2 * t);
    const float2 s2  = *(const float2*)(sd + 2 * t);
    unsigned short* xr = X + (size_t)r * KA;
    unsigned short* yr = Y + (size_t)r * KA;
    const float srv[2] = {s_r.x, s_r.y}, siv[2] = {s_i.x, s_i.y};
    const float cv_[2] = {c2.x, c2.y},  sv_[2] = {s2.x, s2.y};
    ushort2 xh_r, xh_i, xl_r, xl_i, yh_r, yh_i, yl_r, yl_i;
    unsigned short* o[8] = {(unsigned short*)&xh_r, (unsigned short*)&xh_i,
                            (unsigned short*)&xl_r, (unsigned short*)&xl_i,
                            (unsigned short*)&yh_r, (unsigned short*)&yh_i,
                            (unsigned short*)&yl_r, (unsigned short*)&yl_i};
#pragma unroll
    for (int e = 0; e < 2; e++) {
        const unsigned short hr = f2bf(srv[e]);
        const unsigned short hi_ = f2bf(siv[e]);
        o[0][e] = hr;  o[2][e] = f2bf(srv[e] - bf2f(hr));
        o[1][e] = hi_; o[3][e] = f2bf(siv[e] - bf2f(hi_));
        const float krr = srv[e] * cv_[e] + siv[e] * sv_[e];
        const float kri = siv[e] * cv_[e] - srv[e] * sv_[e];
        const unsigned short yh1 = f2bf(krr);
        const unsigned short yh2 = f2bf(kri);
        o[4][e] = yh1; o[6][e] = f2bf(krr - bf2f(yh1));
        o[5][e] = yh2; o[7][e] = f2bf(kri - bf2f(yh2));
    }
    *(ushort2*)(xr + 2 * t)        = xh_r;
    *(ushort2*)(xr + 512 + 2 * t)  = xh_i;
    *(ushort2*)(xr + 1024 + 2 * t) = xl_r;
    *(ushort2*)(xr + 1536 + 2 * t) = xl_i;
    *(ushort2*)(yr + 2 * t)        = yh_r;
    *(ushort2*)(yr + 512 + 2 * t)  = yh_i;
    *(ushort2*)(yr + 1024 + 2 * t) = yl_r;
    *(ushort2*)(yr + 1536 + 2 * t) = yl_i;
}

// ---------------- fused score+softmax: S=scale*(X@Y^T) 3-term, row softmax, bf16-split out ----------------
// M-tile 64 x full 256 q. R3: XCD co-location — the 4 row-tiles of a sample have ids s, s+C, s+2C, s+3C
// (C multiple of 8 -> same XCD -> per-phase Y slices L2-hot).
__global__ __launch_bounds__(256) void k_score_sm(const unsigned short* __restrict__ X,
        const unsigned short* __restrict__ Y,
        unsigned short* __restrict__ Asp, const int* __restrict__ active) {
    if (*active == 0) return;
    __shared__ short XH[64][32], XL[64][32];
    __shared__ short YH[256][32], YL[256][32];
    const int t = threadIdx.x;
    const int w = t >> 6, L = t & 63;
    const int lane15 = L & 15, quad = L >> 4;
    const int nsm = (int)gridDim.x >> 2;           // C (power of 2)
    const int s   = (int)blockIdx.x & (nsm - 1);   // chunk-local sample
    const int rt  = (int)blockIdx.x / nsm;         // row-tile 0..3
    const int bm = s * 256 + rt * 64;              // chunk-local row base
    const int yb = s * 256;                        // sample's Y rows
    const int gr = t >> 2, ch = (t & 3) * 8;
    short* XHw = &XH[0][0] + w * 512;
    short* XLw = &XL[0][0] + w * 512;
    short* YHw = &YH[0][0] + w * 512;
    short* YLw = &YL[0][0] + w * 512;
    f32x4 acc[16] = {};
    for (int k0 = 0; k0 < 1024; k0 += 32) {
        __syncthreads();
        gl2lds16(X + (size_t)(bm + gr) * KA + k0 + ch,        XHw);
        gl2lds16(X + (size_t)(bm + gr) * KA + 1024 + k0 + ch, XLw);
#pragma unroll
        for (int ss = 0; ss < 4; ss++) {
            gl2lds16(Y + (size_t)(yb + ss * 64 + gr) * KA + k0 + ch,        YHw + ss * 2048);
            gl2lds16(Y + (size_t)(yb + ss * 64 + gr) * KA + 1024 + k0 + ch, YLw + ss * 2048);
        }
        __syncthreads();
        const bf16x8 xh = *(const bf16x8*)&XH[w * 16 + lane15][quad * 8];
        const bf16x8 xl = *(const bf16x8*)&XL[w * 16 + lane15][quad * 8];
#pragma unroll
        for (int tc = 0; tc < 16; tc++) {
            const bf16x8 yh = *(const bf16x8*)&YH[tc * 16 + lane15][quad * 8];
            acc[tc] = __builtin_amdgcn_mfma_f32_16x16x32_bf16(xh, yh, acc[tc], 0, 0, 0);
            acc[tc] = __builtin_amdgcn_mfma_f32_16x16x32_bf16(xl, yh, acc[tc], 0, 0, 0);
            const bf16x8 yl = *(const bf16x8*)&YL[tc * 16 + lane15][quad * 8];
            acc[tc] = __builtin_amdgcn_mfma_f32_16x16x32_bf16(xh, yl, acc[tc], 0, 0, 0);
        }
    }
    // softmax epilogue: row = bm + w*16 + quad*4 + r; q = tc*16 + lane15
#pragma unroll
    for (int tc = 0; tc < 16; tc++) acc[tc] *= SCALE_F;
#pragma unroll
    for (int r = 0; r < 4; r++) {
        float mx = acc[0][r];
#pragma unroll
        for (int tc = 1; tc < 16; tc++) mx = fmaxf(mx, acc[tc][r]);
#pragma unroll
        for (int off = 8; off; off >>= 1) mx = fmaxf(mx, __shfl_xor(mx, off, 64));
        float sum = 0.f;
        float e[16];
#pragma unroll
        for (int tc = 0; tc < 16; tc++) { e[tc] = __expf(acc[tc][r] - mx); sum += e[tc]; }
#pragma unroll
        for (int off = 8; off; off >>= 1) sum += __shfl_xor(sum, off, 64);
        const float inv = 1.0f / sum;
        const int row = bm + w * 16 + quad * 4 + r;
        unsigned short* o = Asp + (size_t)row * 512;
#pragma unroll
        for (int tc = 0; tc < 16; tc++) {
            const float p = e[tc] * inv;
            const unsigned short h = f2bf(p);
            o[tc * 16 + lane15] = h;
            o[256 + tc * 16 + lane15] = f2bf(p - bf2f(h));
        }
    }
}

// ---------------- attn_out via split-bf16 MFMA (3-term), fused v-rot + prev-add epilogue ----------------
// R3: grid flipped (x = row-tile, y = d-tile): the 8 d-blocks sharing one Asp tile differ by C*2
// block ids -> same XCD -> staged A slices L2-hot.
__global__ __launch_bounds__(256) void k_attnout_mfma(const unsigned short* __restrict__ Asp,
        const unsigned short* __restrict__ X,
        const float* __restrict__ Sr, const float* __restrict__ Si,
        const float* __restrict__ cv, const float* __restrict__ sv,
        unsigned short* __restrict__ A2, const int* __restrict__ active) {
    if (*active == 0) return;
    __shared__ short AhT[128][32];
    __shared__ short AlT[128][32];
    __shared__ short BH[128][40];   // +8 pad: 80B row stride -> b128 r/w at the bank floor
    __shared__ short BL[128][40];
    const int t = threadIdx.x;
    const int w = t >> 6, L = t & 63;
    const int lane15 = L & 15, quad = L >> 4;
    const int bm = blockIdx.x * 128;          // chunk-local row base (flipped)
    const int bn = blockIdx.y * 64;           // d base (0..448)
    const int sample = blockIdx.x >> 1;       // chunk-local sample
    const int gr = t >> 2, ch = (t & 3) * 8;
    short* AhW0 = &AhT[0][0] + w * 512;
    short* AhW1 = AhW0 + 64 * 32;
    short* AlW0 = &AlT[0][0] + w * 512;
    short* AlW1 = AlW0 + 64 * 32;
    const int nn = t & 127, kh = t >> 7;
    const unsigned short* Bsrc = X + (size_t)sample * PP * KA
                               + ((nn < 64) ? (bn + nn) : (512 + bn + nn - 64));
    f32x4 acc[2][8] = {};
    for (int q0 = 0; q0 < PP; q0 += 32) {
        __syncthreads();
        gl2lds16(Asp + (size_t)(bm + gr) * 512      + q0 + ch,       AhW0);
        gl2lds16(Asp + (size_t)(bm + 64 + gr) * 512 + q0 + ch,       AhW1);
        gl2lds16(Asp + (size_t)(bm + gr) * 512      + 256 + q0 + ch, AlW0);
        gl2lds16(Asp + (size_t)(bm + 64 + gr) * 512 + 256 + q0 + ch, AlW1);
#pragma unroll
        for (int kg = 0; kg < 2; kg++) {
            const int qb = kh * 16 + kg * 8;
            bf16x8 hh, ll;
#pragma unroll
            for (int j = 0; j < 8; j++) {
                const size_t o = (size_t)(q0 + qb + j) * KA;
                hh[j] = (short)Bsrc[o];
                ll[j] = (short)Bsrc[o + 1024];
            }
            *(bf16x8*)&BH[nn][qb] = hh;
            *(bf16x8*)&BL[nn][qb] = ll;
        }
        __syncthreads();
        bf16x8 bh[8];
#pragma unroll
        for (int tc = 0; tc < 8; tc++)
            bh[tc] = *(const bf16x8*)&BH[tc * 16 + lane15][quad * 8];
        bf16x8 afh[2];
#pragma unroll
        for (int tr = 0; tr < 2; tr++) {
            afh[tr] = *(const bf16x8*)&AhT[w * 32 + tr * 16 + lane15][quad * 8];
            const bf16x8 afl = *(const bf16x8*)&AlT[w * 32 + tr * 16 + lane15][quad * 8];
#pragma unroll
            for (int tc = 0; tc < 8; tc++)
                acc[tr][tc] = __builtin_amdgcn_mfma_f32_16x16x32_bf16(afh[tr], bh[tc], acc[tr][tc], 0, 0, 0);
#pragma unroll
            for (int tc = 0; tc < 8; tc++)
                acc[tr][tc] = __builtin_amdgcn_mfma_f32_16x16x32_bf16(afl, bh[tc], acc[tr][tc], 0, 0, 0);
        }
#pragma unroll
        for (int tc = 0; tc < 8; tc++) {
            const bf16x8 bl = *(const bf16x8*)&BL[tc * 16 + lane15][quad * 8];
            acc[0][tc] = __builtin_amdgcn_mfma_f32_16x16x32_bf16(afh[0], bl, acc[0][tc], 0, 0, 0);
            acc[1][tc] = __builtin_amdgcn_mfma_f32_16x16x32_bf16(afh[1], bl, acc[1][tc], 0, 0, 0);
        }
    }
#pragma unroll
    for (int tr = 0; tr < 2; tr++) {
#pragma unroll
        for (int tc = 0; tc < 4; tc++) {
            const int d = bn + tc * 16 + lane15;
            const float cvd = cv[d], svd = sv[d];
#pragma unroll
            for (int r = 0; r < 4; r++) {
                const int m = bm + w * 32 + tr * 16 + quad * 4 + r;  // chunk-local row
                const float wr = acc[tr][tc][r];
                const float wi = acc[tr][tc + 4][r];
                const float tr_ = Sr[(size_t)m * DD + d] + (wr * cvd - wi * svd);
                const float ti_ = Si[(size_t)m * DD + d] + (wr * svd + wi * cvd);
                const unsigned short rh = f2bf(tr_);
                const unsigned short ih = f2bf(ti_);
                unsigned short* arow = A2 + (size_t)m * KA;
                arow[d]        = rh;
                arow[512 + d]  = ih;
                arow[1024 + d] = f2bf(tr_ - bf2f(rh));
                arow[1536 + d] = f2bf(ti_ - bf2f(ih));
            }
        }
    }
}

// ---------------- ff via split-bf16 MFMA, 48-MFMA phases, Bt2=[hi|lo] ----------------
// R3: grid flipped (x = row-tile, y = n-tile): the 8 n-blocks sharing one A2 tile differ by C*2
// block ids -> same XCD.
__global__ __launch_bounds__(256) void k_ff_mfma2(const unsigned short* __restrict__ A2,
        const unsigned short* __restrict__ Bt2,
        float* __restrict__ U, const int* __restrict__ active) {
    if (*active == 0) return;
    __shared__ short AH[128][32], AL[128][32];
    __shared__ short BH[128][32], BL[128][32];
    const int t = threadIdx.x;
    const int w = t >> 6, L = t & 63;
    const int lane15 = L & 15, quad = L >> 4;
    const int bm = blockIdx.x * 128, bn = blockIdx.y * 128;   // flipped
    const int gr = t >> 2, ch = (t & 3) * 8;
    short* AHw = &AH[0][0] + w * 512;
    short* ALw = &AL[0][0] + w * 512;
    short* BHw = &BH[0][0] + w * 512;
    short* BLw = &BL[0][0] + w * 512;
    f32x4 acc[2][8] = {};
    for (int k0 = 0; k0 < 1024; k0 += 32) {
        __syncthreads();
        gl2lds16(A2  + (size_t)(bm + gr) * KA       + k0 + ch,        AHw);
        gl2lds16(A2  + (size_t)(bm + 64 + gr) * KA  + k0 + ch,        AHw + 64 * 32);
        gl2lds16(A2  + (size_t)(bm + gr) * KA       + 1024 + k0 + ch, ALw);
        gl2lds16(A2  + (size_t)(bm + 64 + gr) * KA  + 1024 + k0 + ch, ALw + 64 * 32);
        gl2lds16(Bt2 + (size_t)(bn + gr) * KB2      + k0 + ch,        BHw);
        gl2lds16(Bt2 + (size_t)(bn + 64 + gr) * KB2 + k0 + ch,        BHw + 64 * 32);
        gl2lds16(Bt2 + (size_t)(bn + gr) * KB2      + 1024 + k0 + ch, BLw);
        gl2lds16(Bt2 + (size_t)(bn + 64 + gr) * KB2 + 1024 + k0 + ch, BLw + 64 * 32);
        __syncthreads();
        bf16x8 ah[2], al[2];
#pragma unroll
        for (int tr = 0; tr < 2; tr++) {
            ah[tr] = *(const bf16x8*)&AH[w * 32 + tr * 16 + lane15][quad * 8];
            al[tr] = *(const bf16x8*)&AL[w * 32 + tr * 16 + lane15][quad * 8];
        }
#pragma unroll
        for (int tc = 0; tc < 8; tc++) {
            const bf16x8 bh = *(const bf16x8*)&BH[tc * 16 + lane15][quad * 8];
            acc[0][tc] = __builtin_amdgcn_mfma_f32_16x16x32_bf16(ah[0], bh, acc[0][tc], 0, 0, 0);
            acc[1][tc] = __builtin_amdgcn_mfma_f32_16x16x32_bf16(ah[1], bh, acc[1][tc], 0, 0, 0);
            acc[0][tc] = __builtin_amdgcn_mfma_f32_16x16x32_bf16(al[0], bh, acc[0][tc], 0, 0, 0);
            acc[1][tc] = __builtin_amdgcn_mfma_f32_16x16x32_bf16(al[1], bh, acc[1][tc], 0, 0, 0);
            const bf16x8 bl = *(const bf16x8*)&BL[tc * 16 + lane15][quad * 8];
            acc[0][tc] = __builtin_amdgcn_mfma_f32_16x16x32_bf16(ah[0], bl, acc[0][tc], 0, 0, 0);
            acc[1][tc] = __builtin_amdgcn_mfma_f32_16x16x32_bf16(ah[1], bl, acc[1][tc], 0, 0, 0);
        }
    }
#pragma unroll
    for (int tr = 0; tr < 2; tr++)
#pragma unroll
        for (int tc = 0; tc < 8; tc++) {
            const int n = bn + tc * 16 + lane15;
            const int mbase = bm + w * 32 + tr * 16 + quad * 4;
#pragma unroll
            for (int r = 0; r < 4; r++)
                U[(size_t)(mbase + r) * NK + n] = acc[tr][tc][r];
        }
}

// ---------------- complex_norm + commit + partial + fused X/Y pack ----------------
// NOTE: X overlays U byte-exactly per row; every X store data-depends on all U loads
// (via the cross-lane mean/var reduction), so in-place is safe. No __restrict__ on U/X/Y.
__global__ __launch_bounds__(256) void k_norm(const float* U,
        float* __restrict__ Sr, float* __restrict__ Si,
        float* __restrict__ part,
        unsigned short* X, unsigned short* Y,
        const float* __restrict__ cd, const float* __restrict__ sd,
        const int wxy, const int* __restrict__ active) {
    if (*active == 0) return;
    __shared__ float red[8];
    const int t = threadIdx.x, rt = t >> 6, L = t & 63;
    const int row = blockIdx.x * 4 + rt;
    const size_t ub = (size_t)row * NK;
    const size_t base = (size_t)row * DD;
    const float4 ur0 = *(const float4*)(U + ub + 4 * L);
    const float4 ur1 = *(const float4*)(U + ub + 256 + 4 * L);
    const float4 ui0 = *(const float4*)(U + ub + 512 + 4 * L);
    const float4 ui1 = *(const float4*)(U + ub + 768 + 4 * L);
    const float4 pr0 = *(const float4*)(Sr + base + 4 * L);
    const float4 pr1 = *(const float4*)(Sr + base + 256 + 4 * L);
    const float4 pi0 = *(const float4*)(Si + base + 4 * L);
    const float4 pi1 = *(const float4*)(Si + base + 256 + 4 * L);
    const float urr[8] = {ur0.x, ur0.y, ur0.z, ur0.w, ur1.x, ur1.y, ur1.z, ur1.w};
    const float uii[8] = {ui0.x, ui0.y, ui0.z, ui0.w, ui1.x, ui1.y, ui1.z, ui1.w};
    float mg[8], msum = 0.f;
#pragma unroll
    for (int e = 0; e < 8; e++) {
        mg[e] = sqrtf(urr[e] * urr[e] + uii[e] * uii[e]);
        msum += mg[e];
    }
#pragma unroll
    for (int off = 32; off; off >>= 1) msum += __shfl_xor(msum, off, 64);
    const float mean = msum * (1.0f / 512.0f);
    float vs = 0.f;
#pragma unroll
    for (int e = 0; e < 8; e++) { const float d = mg[e] - mean; vs += d * d; }
#pragma unroll
    for (int off = 32; off; off >>= 1) vs += __shfl_xor(vs, off, 64);
    const float istd = 1.0f / (sqrtf(vs * (1.0f / 511.0f)) + 1e-5f);
    float nr[8], ni[8];
#pragma unroll
    for (int e = 0; e < 8; e++) {
        const float sc = tanhf((mg[e] - mean) * istd) / (mg[e] + 1e-5f);
        nr[e] = urr[e] * sc; ni[e] = uii[e] * sc;
    }
    const float prr[8] = {pr0.x, pr0.y, pr0.z, pr0.w, pr1.x, pr1.y, pr1.z, pr1.w};
    const float pii[8] = {pi0.x, pi0.y, pi0.z, pi0.w, pi1.x, pi1.y, pi1.z, pi1.w};
    float dd = 0.f, nn = 0.f;
#pragma unroll
    for (int e = 0; e < 8; e++) {
        const float dr = nr[e] - prr[e], di = ni[e] - pii[e];
        dd += dr * dr + di * di;
        nn += nr[e] * nr[e] + ni[e] * ni[e];
    }
    *(float4*)(Sr + base + 4 * L)       = make_float4(nr[0], nr[1], nr[2], nr[3]);
    *(float4*)(Sr + base + 256 + 4 * L) = make_float4(nr[4], nr[5], nr[6], nr[7]);
    *(float4*)(Si + base + 4 * L)       = make_float4(ni[0], ni[1], ni[2], ni[3]);
    *(float4*)(Si + base + 256 + 4 * L) = make_float4(ni[4], ni[5], ni[6], ni[7]);
    if (wxy) {
        unsigned short* xr = X + (size_t)row * KA;
        unsigned short* yr = Y + (size_t)row * KA;
        const float4 c0 = *(const float4*)(cd + 4 * L);
        const float4 c1 = *(const float4*)(cd + 256 + 4 * L);
        const float4 s0 = *(const float4*)(sd + 4 * L);
        const float4 s1 = *(const float4*)(sd + 256 + 4 * L);
        const float cdv[8] = {c0.x, c0.y, c0.z, c0.w, c1.x, c1.y, c1.z, c1.w};
        const float sdv[8] = {s0.x, s0.y, s0.z, s0.w, s1.x, s1.y, s1.z, s1.w};
        ushort4 xhr[2], xhi[2], xlr[2], xli[2], yhr[2], yhi[2], ylr[2], yli[2];
#pragma unroll
        for (int e = 0; e < 8; e++) {
            const int g = e >> 2, j = e & 3;
            const unsigned short hr = f2bf(nr[e]);
            const unsigned short hi_ = f2bf(ni[e]);
            ((unsigned short*)&xhr[g])[j] = hr;
            ((unsigned short*)&xlr[g])[j] = f2bf(nr[e] - bf2f(hr));
            ((unsigned short*)&xhi[g])[j] = hi_;
            ((unsigned short*)&xli[g])[j] = f2bf(ni[e] - bf2f(hi_));
            const float krr = nr[e] * cdv[e] + ni[e] * sdv[e];
            const float kri = ni[e] * cdv[e] - nr[e] * sdv[e];
            const unsigned short k1 = f2bf(krr);
            const unsigned short k2 = f2bf(kri);
            ((unsigned short*)&yhr[g])[j] = k1;
            ((unsigned short*)&ylr[g])[j] = f2bf(krr - bf2f(k1));
            ((unsigned short*)&yhi[g])[j] = k2;
            ((unsigned short*)&yli[g])[j] = f2bf(kri - bf2f(k2));
        }
        *(ushort4*)(xr + 4 * L)        = xhr[0]; *(ushort4*)(xr + 256 + 4 * L)  = xhr[1];
        *(ushort4*)(xr + 512 + 4 * L)  = xhi[0]; *(ushort4*)(xr + 768 + 4 * L)  = xhi[1];
        *(ushort4*)(xr + 1024 + 4 * L) = xlr[0]; *(ushort4*)(xr + 1280 + 4 * L) = xlr[1];
        *(ushort4*)(xr + 1536 + 4 * L) = xli[0]; *(ushort4*)(xr + 1792 + 4 * L) = xli[1];
        *(ushort4*)(yr + 4 * L)        = yhr[0]; *(ushort4*)(yr + 256 + 4 * L)  = yhr[1];
        *(ushort4*)(yr + 512 + 4 * L)  = yhi[0]; *(ushort4*)(yr + 768 + 4 * L)  = yhi[1];
        *(ushort4*)(yr + 1024 + 4 * L) = ylr[0]; *(ushort4*)(yr + 1280 + 4 * L) = ylr[1];
        *(ushort4*)(yr + 1536 + 4 * L) = yli[0]; *(ushort4*)(yr + 1792 + 4 * L) = yli[1];
    }
#pragma unroll
    for (int off = 32; off; off >>= 1) {
        dd += __shfl_xor(dd, off, 64);
        nn += __shfl_xor(nn, off, 64);
    }
    if (L == 0) { red[rt] = dd; red[4 + rt] = nn; }
    __syncthreads();
    if (t == 0)
        *(float2*)(part + 2 * blockIdx.x) =
            make_float2(red[0] + red[1] + red[2] + red[3],
                        red[4] + red[5] + red[6] + red[7]);
}

// ---------------- convergence flag: reduce all NSLOT partials ----------------
__global__ __launch_bounds__(256) void k_flag(const float* __restrict__ part, int* __restrict__ active) {
    __shared__ float red[8];
    const int t = threadIdx.x, rt = t >> 6, L = t & 63;
    float dd = 0.f, nn = 0.f;
    for (int i = t; i < NSLOT; i += 256) {
        const float2 p = *(const float2*)(part + 2 * i);
        dd += p.x; nn += p.y;
    }
#pragma unroll
    for (int off = 32; off; off >>= 1) {
        dd += __shfl_xor(dd, off, 64);
        nn += __shfl_xor(nn, off, 64);
    }
    if (L == 0) { red[rt] = dd; red[4 + rt] = nn; }
    __syncthreads();
    if (t == 0) {
        const float d = red[0] + red[1] + red[2] + red[3];
        const float n = red[4] + red[5] + red[6] + red[7];
        const float diff = sqrtf(d) / (sqrtf(n) + 1e-8f);
        const int a = *active;
        *active = (a && (diff >= 1e-3f)) ? 1 : 0;
    }
}

// ---------------- mean over P ----------------
__global__ __launch_bounds__(256) void k_pool(const float* __restrict__ Sr, const float* __restrict__ Si,
        float* __restrict__ Pr, float* __restrict__ Pi) {
    const int gid = blockIdx.x * 256 + threadIdx.x;
    const int b = gid >> 9, d = gid & 511;
    const size_t base = (size_t)b * PP * DD + d;
    float sr = 0.f, si = 0.f;
    for (int p = 0; p < PP; p++) {
        sr += Sr[base + (size_t)p * DD];
        si += Si[base + (size_t)p * DD];
    }
    Pr[gid] = sr * (1.0f / 256.0f);
    Pi[gid] = si * (1.0f / 256.0f);
}

// ---------------- logits ----------------
__global__ __launch_bounds__(64) void k_logits(const float* __restrict__ Pr, const float* __restrict__ Pi,
        const float* __restrict__ Wr, const float* __restrict__ br,
        const float* __restrict__ Wi, const float* __restrict__ bi,
        float* __restrict__ out) {
    const int b = blockIdx.x;
    const int lane = threadIdx.x;
    for (int c = 0; c < CC; c++) {
        float acc = 0.f;
#pragma unroll
        for (int k = 0; k < 8; k++) {
            const int d = lane + 64 * k;
            acc += Pr[b * DD + d] * Wr[c * DD + d] + Pi[b * DD + d] * Wi[c * DD + d];
        }
#pragma unroll
        for (int off = 32; off; off >>= 1) acc += __shfl_xor(acc, off, 64);
        if (lane == 0) out[b * CC + c] = acc + br[c] + bi[c];
    }
}

extern "C" void kernel_launch(void* const* d_in, const int* in_sizes, int n_in,
                              void* d_out, int out_size, void* d_ws, size_t ws_size,
                              hipStream_t stream) {
    const float* x     = (const float*)d_in[0];
    const float* Wp    = (const float*)d_in[1];
    const float* bp    = (const float*)d_in[2];
    const float* q_rot = (const float*)d_in[3];
    const float* k_rot = (const float*)d_in[4];
    const float* v_rot = (const float*)d_in[5];
    const float* ffr   = (const float*)d_in[6];
    const float* ffi   = (const float*)d_in[7];
    const float* Wr    = (const float*)d_in[8];
    const float* br    = (const float*)d_in[9];
    const float* Wi    = (const float*)d_in[10];
    const float* bi    = (const float*)d_in[11];
    float* out = (float*)d_out;

    float* ws = (float*)d_ws;
    const size_t plane = (size_t)MTOT * DD;      // 16,777,216 floats
    const size_t sline = (size_t)PP * DD;

    float* freq = ws;                  // 512
    float* cd   = freq + DD;
    float* sd   = cd + DD;
    float* cv   = sd + DD;
    float* sv   = cv + DD;
    int*   active = (int*)(sv + DD);   // 1
    float* Pr = ws + 4096;             // 65536
    float* Pi = Pr + (size_t)BB * DD;  // 65536
    float* part = Pi + (size_t)BB * DD;        // 2*NSLOT = 16384 floats
    float* Sr = part + 2 * NSLOT;              // fp32 state (128 MiB)
    float* Si = Sr + plane;
    unsigned short* Bt2 = (unsigned short*)(Si + plane);   // 1024x2048 bf16 (4 MB)
    float* chunkbase = Si + plane + (size_t)NK * 3072 / 2; // 6MB hole reserved (Bt2 fits)

    const size_t fixed_f = (4096 + 2 * (size_t)BB * DD + 2 * NSLOT) + 2 * plane + (size_t)NK * 3072 / 2;
    // per-sample: X/U overlay (1 MB) + Y/A2 overlay (1 MB) + Asp (256 KB) = 2.25 MB
    const size_t perC_f = (size_t)PP * NK * 2 + (size_t)PP * 256;   // 589824 floats

    int C = BB;
    while (C > 1 && (fixed_f + (size_t)C * perC_f) * 4ull > ws_size) C >>= 1;
    const int fullXY = (C == BB);      // X/Y persist across iterations -> norm packs them

    float* U = chunkbase;                                       // C x 256 x 1024 fp32
    unsigned short* X  = (unsigned short*)chunkbase;            // overlay: X dead before ff writes U
    float* Yf = chunkbase + (size_t)C * PP * NK;
    unsigned short* Y  = (unsigned short*)Yf;                   // C x 256 x 2048 bf16
    unsigned short* A2 = Y;                                     // overlay: Y dead after k_score_sm
    unsigned short* Asp = (unsigned short*)(Yf + (size_t)C * PP * NK);  // C x 256 x 512 bf16

    k_setup<<<1, 512, 0, stream>>>(q_rot, k_rot, v_rot, freq, cd, sd, cv, sv, active);
    k_prep2<<<NK, 256, 0, stream>>>(ffr, ffi, Bt2);
    k_init<<<dim3(DD / 64, MTOT / 64), 256, 0, stream>>>(x, Wp, bp, freq, Sr, Si);

    for (int it = 0; it < 4; ++it) {
        for (int c0 = 0; c0 < BB; c0 += C) {
            float* Sr_c = Sr + (size_t)c0 * sline;
            float* Si_c = Si + (size_t)c0 * sline;
            float* part_c = part + (size_t)c0 * (PP / 4) * 2;
            if (!fullXY || it == 0)
                k_xy<<<C * PP, 256, 0, stream>>>(Sr_c, Si_c, cd, sd, X, Y, active);
            k_score_sm<<<C * 4, 256, 0, stream>>>(X, Y, Asp, active);
            k_attnout_mfma<<<dim3(C * 2, 8), 256, 0, stream>>>(Asp, X, Sr_c, Si_c, cv, sv, A2, active);
            k_ff_mfma2<<<dim3(C * 2, NK / 128), 256, 0, stream>>>(A2, Bt2, U, active);
            k_norm<<<C * (PP / 4), 256, 0, stream>>>(U, Sr_c, Si_c, part_c, X, Y, cd, sd, fullXY, active);
        }
        k_flag<<<1, 256, 0, stream>>>(part, active);
    }

    k_pool<<<BB * DD / 256, 256, 0, stream>>>(Sr, Si, Pr, Pi);
    k_logits<<<BB, 64, 0, stream>>>(Pr, Pi, Wr, br, Wi, bi, out);
}

// Round 6
// 3003.101 us; speedup vs baseline: 1.3919x; 1.0015x over previous
//
#include <hip/hip_runtime.h>
#include <math.h>

#define BB   128
#define PP   256
#define PIX_ 256
#define DD   512
#define CC   10
#define MTOT (BB*PP)   // 32768
#define NK   1024      // packed complex N for the ff GEMM
#define KA   2048      // A2 / X / Y row length (hi|lo)
#define KB2  2048      // Bt2 row length (hi|lo)
#define NSLOT (MTOT/4) // 8192 partial slots (one per norm block, whole batch)

static constexpr float SCALE_F = 0.35355339059327373f; // 8/sqrt(512)
static constexpr float PI_F    = 3.14159265358979323846f;

typedef short bf16x8 __attribute__((ext_vector_type(8)));
typedef float f32x4  __attribute__((ext_vector_type(4)));
typedef unsigned short ushort8 __attribute__((ext_vector_type(8)));

__device__ __forceinline__ unsigned short f2bf(float f) {
    union { float f; unsigned u; } v; v.f = f;
    unsigned r = v.u + 0x7FFF + ((v.u >> 16) & 1);   // RNE
    return (unsigned short)(r >> 16);
}
__device__ __forceinline__ float bf2f(unsigned short h) {
    union { unsigned u; float f; } v; v.u = ((unsigned)h) << 16;
    return v.f;
}

// async global->LDS, 16B per lane; LDS dest = wave-uniform base + lane*16B (m97 pattern)
typedef __attribute__((address_space(3))) unsigned lds_u32;
typedef __attribute__((address_space(1))) const unsigned glb_u32;
__device__ __forceinline__ void gl2lds16(const unsigned short* g, short* l) {
    __builtin_amdgcn_global_load_lds((glb_u32*)g, (lds_u32*)l, 16, 0, 0);
}

// ---------------- setup ----------------
__global__ void k_setup(const float* __restrict__ q_rot, const float* __restrict__ k_rot,
                        const float* __restrict__ v_rot,
                        float* __restrict__ freq, float* __restrict__ cd, float* __restrict__ sd,
                        float* __restrict__ cv, float* __restrict__ sv,
                        int* __restrict__ active) {
    int t = threadIdx.x;
    if (t < DD) {
        freq[t] = expf(-(float)t * (9.210340371976184f / 512.0f)); // 10000^(-d/512)
        float dl = q_rot[t] - k_rot[t];
        cd[t] = cosf(dl);       sd[t] = sinf(dl);
        cv[t] = cosf(v_rot[t]); sv[t] = sinf(v_rot[t]);
    }
    if (t == 0) *active = 1;
}

// ---------------- R5: positional phase tables Tc/Ts[256][512] (1 MB, L2-resident) ----------------
__global__ __launch_bounds__(256) void k_tab(const float* __restrict__ freq,
                                             float* __restrict__ Tc, float* __restrict__ Ts) {
    const int p = blockIdx.x, t = threadIdx.x;
#pragma unroll
    for (int j = 0; j < 2; j++) {
        const int d = t * 2 + j;
        float s, c; sincosf((float)p * freq[d] * PI_F, &s, &c);
        Tc[(size_t)p * DD + d] = c;
        Ts[(size_t)p * DD + d] = s;
    }
}

// ---------------- build Bt2[n][0:2048] = [Bhi | Blo] (k-major) ----------------
__global__ __launch_bounds__(256) void k_prep2(const float* __restrict__ Fr, const float* __restrict__ Fi,
                                               unsigned short* __restrict__ Bt2) {
    const int n = blockIdx.x;           // 0..1023
    const int t = threadIdx.x;
    unsigned short* row = Bt2 + (size_t)n * KB2;
#pragma unroll
    for (int j4 = 0; j4 < 4; j4++) {
        const int j = j4 * 256 + t;
        float v;
        if (n < 512) v = (j < 512) ? Fr[(size_t)j * DD + n] : -Fi[(size_t)(j - 512) * DD + n];
        else         v = (j < 512) ? Fi[(size_t)j * DD + (n - 512)] : Fr[(size_t)(j - 512) * DD + (n - 512)];
        const unsigned short hi = f2bf(v);
        row[j] = hi;
        row[NK + j] = f2bf(v - bf2f(hi));
    }
}

#define SCAT4(TILE, V4) do { TILE[lk+0][lrow]=(V4).x; TILE[lk+1][lrow]=(V4).y; \
                             TILE[lk+2][lrow]=(V4).z; TILE[lk+3][lrow]=(V4).w; } while(0)

// ---------------- init: state = tanh(x@Wp^T + bp) * e^{i*p*freq*pi} ----------------
// R5: phase from Tc/Ts table lookup (bit-identical to inline sincosf), kills 16.8M sincos calls
__global__ __launch_bounds__(256) void k_init(const float* __restrict__ x,
        const float* __restrict__ Wp, const float* __restrict__ bp,
        const float* __restrict__ Tc, const float* __restrict__ Ts,
        float* __restrict__ Sr, float* __restrict__ Si) {
    __shared__ float As[16][68];
    __shared__ float Bs[16][68];
    const int bm = blockIdx.y * 64, bn = blockIdx.x * 64;
    const int t = threadIdx.x, tx = t & 15, ty = t >> 4;
    const int lrow = t >> 2, lk = (t & 3) * 4;
    float acc[4][4] = {};
    for (int k0 = 0; k0 < PIX_; k0 += 16) {
        const float4 a4 = *(const float4*)(x  + (size_t)(bm + lrow) * PIX_ + k0 + lk);
        const float4 b4 = *(const float4*)(Wp + (size_t)(bn + lrow) * PIX_ + k0 + lk);
        __syncthreads();
        SCAT4(As, a4);
        SCAT4(Bs, b4);
        __syncthreads();
#pragma unroll
        for (int kk = 0; kk < 16; ++kk) {
            const float4 av = *(const float4*)&As[kk][ty * 4];
            const float4 bv = *(const float4*)&Bs[kk][tx * 4];
            const float a[4] = {av.x, av.y, av.z, av.w};
            const float b[4] = {bv.x, bv.y, bv.z, bv.w};
#pragma unroll
            for (int i = 0; i < 4; i++)
#pragma unroll
                for (int j = 0; j < 4; j++) acc[i][j] = fmaf(a[i], b[j], acc[i][j]);
        }
    }
#pragma unroll
    for (int i = 0; i < 4; i++) {
        const int m = bm + ty * 4 + i;
        const int p = m & 255;
        const float4 c4 = *(const float4*)(Tc + (size_t)p * DD + bn + tx * 4);
        const float4 s4 = *(const float4*)(Ts + (size_t)p * DD + bn + tx * 4);
        const float cphv[4] = {c4.x, c4.y, c4.z, c4.w};
        const float sphv[4] = {s4.x, s4.y, s4.z, s4.w};
        float4 vr, vi;
        float* pvr = (float*)&vr; float* pvi = (float*)&vi;
#pragma unroll
        for (int j = 0; j < 4; j++) {
            const int d = bn + tx * 4 + j;
            const float mg = tanhf(acc[i][j] + bp[d]);
            pvr[j] = mg * cphv[j]; pvi[j] = mg * sphv[j];
        }
        *(float4*)(Sr + (size_t)m * DD + bn + tx * 4) = vr;
        *(float4*)(Si + (size_t)m * DD + bn + tx * 4) = vi;
    }
}

// ---------------- X/Y pack (it=0 + fallback) ---------------- (R12-proven)
__global__ __launch_bounds__(256) void k_xy(const float* __restrict__ Sr, const float* __restrict__ Si,
        const float* __restrict__ cd, const float* __restrict__ sd,
        unsigned short* X, unsigned short* Y,
        const int* __restrict__ active) {
    if (*active == 0) return;
    const int r = blockIdx.x, t = threadIdx.x;
    const size_t base = (size_t)r * DD + 2 * t;
    const float2 s_r = *(const float2*)(Sr + base);
    const float2 s_i = *(const float2*)(Si + base);
    const float2 c2  = *(const float2*)(cd + 2 * t);
    const float2 s2  = *(const float2*)(sd + 2 * t);
    unsigned short* xr = X + (size_t)r * KA;
    unsigned short* yr = Y + (size_t)r * KA;
    const float srv[2] = {s_r.x, s_r.y}, siv[2] = {s_i.x, s_i.y};
    const float cv_[2] = {c2.x, c2.y},  sv_[2] = {s2.x, s2.y};
    ushort2 xh_r, xh_i, xl_r, xl_i, yh_r, yh_i, yl_r, yl_i;
    unsigned short* o[8] = {(unsigned short*)&xh_r, (unsigned short*)&xh_i,
                            (unsigned short*)&xl_r, (unsigned short*)&xl_i,
                            (unsigned short*)&yh_r, (unsigned short*)&yh_i,
                            (unsigned short*)&yl_r, (unsigned short*)&yl_i};
#pragma unroll
    for (int e = 0; e < 2; e++) {
        const unsigned short hr = f2bf(srv[e]);
        const unsigned short hi_ = f2bf(siv[e]);
        o[0][e] = hr;  o[2][e] = f2bf(srv[e] - bf2f(hr));
        o[1][e] = hi_; o[3][e] = f2bf(siv[e] - bf2f(hi_));
        const float krr = srv[e] * cv_[e] + siv[e] * sv_[e];
        const float kri = siv[e] * cv_[e] - srv[e] * sv_[e];
        const unsigned short yh1 = f2bf(krr);
        const unsigned short yh2 = f2bf(kri);
        o[4][e] = yh1; o[6][e] = f2bf(krr - bf2f(yh1));
        o[5][e] = yh2; o[7][e] = f2bf(kri - bf2f(yh2));
    }
    *(ushort2*)(xr + 2 * t)        = xh_r;
    *(ushort2*)(xr + 512 + 2 * t)  = xh_i;
    *(ushort2*)(xr + 1024 + 2 * t) = xl_r;
    *(ushort2*)(xr + 1536 + 2 * t) = xl_i;
    *(ushort2*)(yr + 2 * t)        = yh_r;
    *(ushort2*)(yr + 512 + 2 * t)  = yh_i;
    *(ushort2*)(yr + 1024 + 2 * t) = yl_r;
    *(ushort2*)(yr + 1536 + 2 * t) = yl_i;
}

// ---------------- fused score+softmax: S=scale*(X@Y^T) 3-term, row softmax, bf16-split out ----------------
// R5: flat LDS; epilogue normalizes acc in place, stages hi/lo transposed in LDS (row stride 520),
// then writes Asp as linear 16B stores (was 128 scalar 2B stores/thread).
__global__ __launch_bounds__(256) void k_score_sm(const unsigned short* __restrict__ X,
        const unsigned short* __restrict__ Y,
        unsigned short* __restrict__ Asp, const int* __restrict__ active) {
    if (*active == 0) return;
    __shared__ short SM[20480];            // 40 KB: XH|XL|YH|YL during K-loop; transpose buf in epilogue
    short* XH = SM;                        // [64][32]
    short* XL = SM + 2048;                 // [64][32]
    short* YH = SM + 4096;                 // [256][32]
    short* YL = SM + 12288;                // [256][32]
    const int t = threadIdx.x;
    const int w = t >> 6, L = t & 63;
    const int lane15 = L & 15, quad = L >> 4;
    const int nsm = (int)gridDim.x >> 2;           // C (power of 2)
    const int s   = (int)blockIdx.x & (nsm - 1);   // chunk-local sample
    const int rt  = (int)blockIdx.x / nsm;         // row-tile 0..3
    const int bm = s * 256 + rt * 64;              // chunk-local row base
    const int yb = s * 256;                        // sample's Y rows
    const int gr = t >> 2, ch = (t & 3) * 8;
    short* XHw = XH + w * 512;
    short* XLw = XL + w * 512;
    short* YHw = YH + w * 512;
    short* YLw = YL + w * 512;
    f32x4 acc[16] = {};
    for (int k0 = 0; k0 < 1024; k0 += 32) {
        __syncthreads();
        gl2lds16(X + (size_t)(bm + gr) * KA + k0 + ch,        XHw);
        gl2lds16(X + (size_t)(bm + gr) * KA + 1024 + k0 + ch, XLw);
#pragma unroll
        for (int ss = 0; ss < 4; ss++) {
            gl2lds16(Y + (size_t)(yb + ss * 64 + gr) * KA + k0 + ch,        YHw + ss * 2048);
            gl2lds16(Y + (size_t)(yb + ss * 64 + gr) * KA + 1024 + k0 + ch, YLw + ss * 2048);
        }
        __syncthreads();
        const bf16x8 xh = *(const bf16x8*)(XH + (w * 16 + lane15) * 32 + quad * 8);
        const bf16x8 xl = *(const bf16x8*)(XL + (w * 16 + lane15) * 32 + quad * 8);
#pragma unroll
        for (int tc = 0; tc < 16; tc++) {
            const bf16x8 yh = *(const bf16x8*)(YH + (tc * 16 + lane15) * 32 + quad * 8);
            acc[tc] = __builtin_amdgcn_mfma_f32_16x16x32_bf16(xh, yh, acc[tc], 0, 0, 0);
            acc[tc] = __builtin_amdgcn_mfma_f32_16x16x32_bf16(xl, yh, acc[tc], 0, 0, 0);
            const bf16x8 yl = *(const bf16x8*)(YL + (tc * 16 + lane15) * 32 + quad * 8);
            acc[tc] = __builtin_amdgcn_mfma_f32_16x16x32_bf16(xh, yl, acc[tc], 0, 0, 0);
        }
    }
    // ---- softmax, normalized in place: acc[tc][r] <- p ----
#pragma unroll
    for (int tc = 0; tc < 16; tc++) acc[tc] *= SCALE_F;
#pragma unroll
    for (int r = 0; r < 4; r++) {
        float mx = acc[0][r];
#pragma unroll
        for (int tc = 1; tc < 16; tc++) mx = fmaxf(mx, acc[tc][r]);
#pragma unroll
        for (int off = 8; off; off >>= 1) mx = fmaxf(mx, __shfl_xor(mx, off, 64));
        float sum = 0.f;
#pragma unroll
        for (int tc = 0; tc < 16; tc++) { acc[tc][r] = __expf(acc[tc][r] - mx); sum += acc[tc][r]; }
#pragma unroll
        for (int off = 8; off; off >>= 1) sum += __shfl_xor(sum, off, 64);
        const float inv = 1.0f / sum;
#pragma unroll
        for (int tc = 0; tc < 16; tc++) acc[tc][r] *= inv;
    }
    // ---- transposed store: half h holds rows h*32..h*32+31 (waves 2h, 2h+1) ----
    __syncthreads();   // all waves done reading SM from the K-loop
#pragma unroll
    for (int h = 0; h < 2; h++) {
        if ((w >> 1) == h) {
#pragma unroll
            for (int r = 0; r < 4; r++) {
                const int lr = (w & 1) * 16 + quad * 4 + r;     // 0..31
#pragma unroll
                for (int tc = 0; tc < 16; tc++) {
                    const float p = acc[tc][r];
                    const unsigned short hi = f2bf(p);
                    SM[lr * 520 + tc * 16 + lane15] = (short)hi;
                    SM[lr * 520 + 256 + tc * 16 + lane15] = (short)f2bf(p - bf2f(hi));
                }
            }
        }
        __syncthreads();
        // copy out 32 rows x 512 shorts as linear 16B stores
        unsigned short* dst = Asp + (size_t)(bm + h * 32) * 512;
#pragma unroll
        for (int k = 0; k < 8; k++) {
            const int c = t + 256 * k;            // chunk 0..2047
            const int row = c >> 6, off = (c & 63) * 8;
            *(ushort8*)(dst + (size_t)c * 8) = *(const ushort8*)&SM[row * 520 + off];
        }
        __syncthreads();
    }
}

// ---------------- attn_out via split-bf16 MFMA (3-term), fused v-rot + prev-add epilogue ----------------
// R3: grid flipped (x = row-tile, y = d-tile): the 8 d-blocks sharing one Asp tile differ by C*2
// block ids -> same XCD -> staged A slices L2-hot.
__global__ __launch_bounds__(256) void k_attnout_mfma(const unsigned short* __restrict__ Asp,
        const unsigned short* __restrict__ X,
        const float* __restrict__ Sr, const float* __restrict__ Si,
        const float* __restrict__ cv, const float* __restrict__ sv,
        unsigned short* __restrict__ A2, const int* __restrict__ active) {
    if (*active == 0) return;
    __shared__ short AhT[128][32];
    __shared__ short AlT[128][32];
    __shared__ short BH[128][40];   // +8 pad: 80B row stride -> b128 r/w at the bank floor
    __shared__ short BL[128][40];
    const int t = threadIdx.x;
    const int w = t >> 6, L = t & 63;
    const int lane15 = L & 15, quad = L >> 4;
    const int bm = blockIdx.x * 128;          // chunk-local row base (flipped)
    const int bn = blockIdx.y * 64;           // d base (0..448)
    const int sample = blockIdx.x >> 1;       // chunk-local sample
    const int gr = t >> 2, ch = (t & 3) * 8;
    short* AhW0 = &AhT[0][0] + w * 512;
    short* AhW1 = AhW0 + 64 * 32;
    short* AlW0 = &AlT[0][0] + w * 512;
    short* AlW1 = AlW0 + 64 * 32;
    const int nn = t & 127, kh = t >> 7;
    const unsigned short* Bsrc = X + (size_t)sample * PP * KA
                               + ((nn < 64) ? (bn + nn) : (512 + bn + nn - 64));
    f32x4 acc[2][8] = {};
    for (int q0 = 0; q0 < PP; q0 += 32) {
        __syncthreads();
        gl2lds16(Asp + (size_t)(bm + gr) * 512      + q0 + ch,       AhW0);
        gl2lds16(Asp + (size_t)(bm + 64 + gr) * 512 + q0 + ch,       AhW1);
        gl2lds16(Asp + (size_t)(bm + gr) * 512      + 256 + q0 + ch, AlW0);
        gl2lds16(Asp + (size_t)(bm + 64 + gr) * 512 + 256 + q0 + ch, AlW1);
#pragma unroll
        for (int kg = 0; kg < 2; kg++) {
            const int qb = kh * 16 + kg * 8;
            bf16x8 hh, ll;
#pragma unroll
            for (int j = 0; j < 8; j++) {
                const size_t o = (size_t)(q0 + qb + j) * KA;
                hh[j] = (short)Bsrc[o];
                ll[j] = (short)Bsrc[o + 1024];
            }
            *(bf16x8*)&BH[nn][qb] = hh;
            *(bf16x8*)&BL[nn][qb] = ll;
        }
        __syncthreads();
        bf16x8 bh[8];
#pragma unroll
        for (int tc = 0; tc < 8; tc++)
            bh[tc] = *(const bf16x8*)&BH[tc * 16 + lane15][quad * 8];
        bf16x8 afh[2];
#pragma unroll
        for (int tr = 0; tr < 2; tr++) {
            afh[tr] = *(const bf16x8*)&AhT[w * 32 + tr * 16 + lane15][quad * 8];
            const bf16x8 afl = *(const bf16x8*)&AlT[w * 32 + tr * 16 + lane15][quad * 8];
#pragma unroll
            for (int tc = 0; tc < 8; tc++)
                acc[tr][tc] = __builtin_amdgcn_mfma_f32_16x16x32_bf16(afh[tr], bh[tc], acc[tr][tc], 0, 0, 0);
#pragma unroll
            for (int tc = 0; tc < 8; tc++)
                acc[tr][tc] = __builtin_amdgcn_mfma_f32_16x16x32_bf16(afl, bh[tc], acc[tr][tc], 0, 0, 0);
        }
#pragma unroll
        for (int tc = 0; tc < 8; tc++) {
            const bf16x8 bl = *(const bf16x8*)&BL[tc * 16 + lane15][quad * 8];
            acc[0][tc] = __builtin_amdgcn_mfma_f32_16x16x32_bf16(afh[0], bl, acc[0][tc], 0, 0, 0);
            acc[1][tc] = __builtin_amdgcn_mfma_f32_16x16x32_bf16(afh[1], bl, acc[1][tc], 0, 0, 0);
        }
    }
#pragma unroll
    for (int tr = 0; tr < 2; tr++) {
#pragma unroll
        for (int tc = 0; tc < 4; tc++) {
            const int d = bn + tc * 16 + lane15;
            const float cvd = cv[d], svd = sv[d];
#pragma unroll
            for (int r = 0; r < 4; r++) {
                const int m = bm + w * 32 + tr * 16 + quad * 4 + r;  // chunk-local row
                const float wr = acc[tr][tc][r];
                const float wi = acc[tr][tc + 4][r];
                const float tr_ = Sr[(size_t)m * DD + d] + (wr * cvd - wi * svd);
                const float ti_ = Si[(size_t)m * DD + d] + (wr * svd + wi * cvd);
                const unsigned short rh = f2bf(tr_);
                const unsigned short ih = f2bf(ti_);
                unsigned short* arow = A2 + (size_t)m * KA;
                arow[d]        = rh;
                arow[512 + d]  = ih;
                arow[1024 + d] = f2bf(tr_ - bf2f(rh));
                arow[1536 + d] = f2bf(ti_ - bf2f(ih));
            }
        }
    }
}

// ---------------- ff via split-bf16 MFMA, 48-MFMA phases, Bt2=[hi|lo] ----------------
// R3: grid flipped (x = row-tile, y = n-tile): the 8 n-blocks sharing one A2 tile differ by C*2
// block ids -> same XCD.
__global__ __launch_bounds__(256) void k_ff_mfma2(const unsigned short* __restrict__ A2,
        const unsigned short* __restrict__ Bt2,
        float* __restrict__ U, const int* __restrict__ active) {
    if (*active == 0) return;
    __shared__ short AH[128][32], AL[128][32];
    __shared__ short BH[128][32], BL[128][32];
    const int t = threadIdx.x;
    const int w = t >> 6, L = t & 63;
    const int lane15 = L & 15, quad = L >> 4;
    const int bm = blockIdx.x * 128, bn = blockIdx.y * 128;   // flipped
    const int gr = t >> 2, ch = (t & 3) * 8;
    short* AHw = &AH[0][0] + w * 512;
    short* ALw = &AL[0][0] + w * 512;
    short* BHw = &BH[0][0] + w * 512;
    short* BLw = &BL[0][0] + w * 512;
    f32x4 acc[2][8] = {};
    for (int k0 = 0; k0 < 1024; k0 += 32) {
        __syncthreads();
        gl2lds16(A2  + (size_t)(bm + gr) * KA       + k0 + ch,        AHw);
        gl2lds16(A2  + (size_t)(bm + 64 + gr) * KA  + k0 + ch,        AHw + 64 * 32);
        gl2lds16(A2  + (size_t)(bm + gr) * KA       + 1024 + k0 + ch, ALw);
        gl2lds16(A2  + (size_t)(bm + 64 + gr) * KA  + 1024 + k0 + ch, ALw + 64 * 32);
        gl2lds16(Bt2 + (size_t)(bn + gr) * KB2      + k0 + ch,        BHw);
        gl2lds16(Bt2 + (size_t)(bn + 64 + gr) * KB2 + k0 + ch,        BHw + 64 * 32);
        gl2lds16(Bt2 + (size_t)(bn + gr) * KB2      + 1024 + k0 + ch, BLw);
        gl2lds16(Bt2 + (size_t)(bn + 64 + gr) * KB2 + 1024 + k0 + ch, BLw + 64 * 32);
        __syncthreads();
        bf16x8 ah[2], al[2];
#pragma unroll
        for (int tr = 0; tr < 2; tr++) {
            ah[tr] = *(const bf16x8*)&AH[w * 32 + tr * 16 + lane15][quad * 8];
            al[tr] = *(const bf16x8*)&AL[w * 32 + tr * 16 + lane15][quad * 8];
        }
#pragma unroll
        for (int tc = 0; tc < 8; tc++) {
            const bf16x8 bh = *(const bf16x8*)&BH[tc * 16 + lane15][quad * 8];
            acc[0][tc] = __builtin_amdgcn_mfma_f32_16x16x32_bf16(ah[0], bh, acc[0][tc], 0, 0, 0);
            acc[1][tc] = __builtin_amdgcn_mfma_f32_16x16x32_bf16(ah[1], bh, acc[1][tc], 0, 0, 0);
            acc[0][tc] = __builtin_amdgcn_mfma_f32_16x16x32_bf16(al[0], bh, acc[0][tc], 0, 0, 0);
            acc[1][tc] = __builtin_amdgcn_mfma_f32_16x16x32_bf16(al[1], bh, acc[1][tc], 0, 0, 0);
            const bf16x8 bl = *(const bf16x8*)&BL[tc * 16 + lane15][quad * 8];
            acc[0][tc] = __builtin_amdgcn_mfma_f32_16x16x32_bf16(ah[0], bl, acc[0][tc], 0, 0, 0);
            acc[1][tc] = __builtin_amdgcn_mfma_f32_16x16x32_bf16(ah[1], bl, acc[1][tc], 0, 0, 0);
        }
    }
#pragma unroll
    for (int tr = 0; tr < 2; tr++)
#pragma unroll
        for (int tc = 0; tc < 8; tc++) {
            const int n = bn + tc * 16 + lane15;
            const int mbase = bm + w * 32 + tr * 16 + quad * 4;
#pragma unroll
            for (int r = 0; r < 4; r++)
                U[(size_t)(mbase + r) * NK + n] = acc[tr][tc][r];
        }
}

// ---------------- complex_norm + commit + partial + fused X/Y pack ----------------
// NOTE: X overlays U byte-exactly per row; every X store data-depends on all U loads
// (via the cross-lane mean/var reduction), so in-place is safe. No __restrict__ on U/X/Y.
__global__ __launch_bounds__(256) void k_norm(const float* U,
        float* __restrict__ Sr, float* __restrict__ Si,
        float* __restrict__ part,
        unsigned short* X, unsigned short* Y,
        const float* __restrict__ cd, const float* __restrict__ sd,
        const int wxy, const int* __restrict__ active) {
    if (*active == 0) return;
    __shared__ float red[8];
    const int t = threadIdx.x, rt = t >> 6, L = t & 63;
    const int row = blockIdx.x * 4 + rt;
    const size_t ub = (size_t)row * NK;
    const size_t base = (size_t)row * DD;
    const float4 ur0 = *(const float4*)(U + ub + 4 * L);
    const float4 ur1 = *(const float4*)(U + ub + 256 + 4 * L);
    const float4 ui0 = *(const float4*)(U + ub + 512 + 4 * L);
    const float4 ui1 = *(const float4*)(U + ub + 768 + 4 * L);
    const float4 pr0 = *(const float4*)(Sr + base + 4 * L);
    const float4 pr1 = *(const float4*)(Sr + base + 256 + 4 * L);
    const float4 pi0 = *(const float4*)(Si + base + 4 * L);
    const float4 pi1 = *(const float4*)(Si + base + 256 + 4 * L);
    const float urr[8] = {ur0.x, ur0.y, ur0.z, ur0.w, ur1.x, ur1.y, ur1.z, ur1.w};
    const float uii[8] = {ui0.x, ui0.y, ui0.z, ui0.w, ui1.x, ui1.y, ui1.z, ui1.w};
    float mg[8], msum = 0.f;
#pragma unroll
    for (int e = 0; e < 8; e++) {
        mg[e] = sqrtf(urr[e] * urr[e] + uii[e] * uii[e]);
        msum += mg[e];
    }
#pragma unroll
    for (int off = 32; off; off >>= 1) msum += __shfl_xor(msum, off, 64);
    const float mean = msum * (1.0f / 512.0f);
    float vs = 0.f;
#pragma unroll
    for (int e = 0; e < 8; e++) { const float d = mg[e] - mean; vs += d * d; }
#pragma unroll
    for (int off = 32; off; off >>= 1) vs += __shfl_xor(vs, off, 64);
    const float istd = 1.0f / (sqrtf(vs * (1.0f / 511.0f)) + 1e-5f);
    float nr[8], ni[8];
#pragma unroll
    for (int e = 0; e < 8; e++) {
        const float sc = tanhf((mg[e] - mean) * istd) / (mg[e] + 1e-5f);
        nr[e] = urr[e] * sc; ni[e] = uii[e] * sc;
    }
    const float prr[8] = {pr0.x, pr0.y, pr0.z, pr0.w, pr1.x, pr1.y, pr1.z, pr1.w};
    const float pii[8] = {pi0.x, pi0.y, pi0.z, pi0.w, pi1.x, pi1.y, pi1.z, pi1.w};
    float dd = 0.f, nn = 0.f;
#pragma unroll
    for (int e = 0; e < 8; e++) {
        const float dr = nr[e] - prr[e], di = ni[e] - pii[e];
        dd += dr * dr + di * di;
        nn += nr[e] * nr[e] + ni[e] * ni[e];
    }
    *(float4*)(Sr + base + 4 * L)       = make_float4(nr[0], nr[1], nr[2], nr[3]);
    *(float4*)(Sr + base + 256 + 4 * L) = make_float4(nr[4], nr[5], nr[6], nr[7]);
    *(float4*)(Si + base + 4 * L)       = make_float4(ni[0], ni[1], ni[2], ni[3]);
    *(float4*)(Si + base + 256 + 4 * L) = make_float4(ni[4], ni[5], ni[6], ni[7]);
    if (wxy) {
        unsigned short* xr = X + (size_t)row * KA;
        unsigned short* yr = Y + (size_t)row * KA;
        const float4 c0 = *(const float4*)(cd + 4 * L);
        const float4 c1 = *(const float4*)(cd + 256 + 4 * L);
        const float4 s0 = *(const float4*)(sd + 4 * L);
        const float4 s1 = *(const float4*)(sd + 256 + 4 * L);
        const float cdv[8] = {c0.x, c0.y, c0.z, c0.w, c1.x, c1.y, c1.z, c1.w};
        const float sdv[8] = {s0.x, s0.y, s0.z, s0.w, s1.x, s1.y, s1.z, s1.w};
        ushort4 xhr[2], xhi[2], xlr[2], xli[2], yhr[2], yhi[2], ylr[2], yli[2];
#pragma unroll
        for (int e = 0; e < 8; e++) {
            const int g = e >> 2, j = e & 3;
            const unsigned short hr = f2bf(nr[e]);
            const unsigned short hi_ = f2bf(ni[e]);
            ((unsigned short*)&xhr[g])[j] = hr;
            ((unsigned short*)&xlr[g])[j] = f2bf(nr[e] - bf2f(hr));
            ((unsigned short*)&xhi[g])[j] = hi_;
            ((unsigned short*)&xli[g])[j] = f2bf(ni[e] - bf2f(hi_));
            const float krr = nr[e] * cdv[e] + ni[e] * sdv[e];
            const float kri = ni[e] * cdv[e] - nr[e] * sdv[e];
            const unsigned short k1 = f2bf(krr);
            const unsigned short k2 = f2bf(kri);
            ((unsigned short*)&yhr[g])[j] = k1;
            ((unsigned short*)&ylr[g])[j] = f2bf(krr - bf2f(k1));
            ((unsigned short*)&yhi[g])[j] = k2;
            ((unsigned short*)&yli[g])[j] = f2bf(kri - bf2f(k2));
        }
        *(ushort4*)(xr + 4 * L)        = xhr[0]; *(ushort4*)(xr + 256 + 4 * L)  = xhr[1];
        *(ushort4*)(xr + 512 + 4 * L)  = xhi[0]; *(ushort4*)(xr + 768 + 4 * L)  = xhi[1];
        *(ushort4*)(xr + 1024 + 4 * L) = xlr[0]; *(ushort4*)(xr + 1280 + 4 * L) = xlr[1];
        *(ushort4*)(xr + 1536 + 4 * L) = xli[0]; *(ushort4*)(xr + 1792 + 4 * L) = xli[1];
        *(ushort4*)(yr + 4 * L)        = yhr[0]; *(ushort4*)(yr + 256 + 4 * L)  = yhr[1];
        *(ushort4*)(yr + 512 + 4 * L)  = yhi[0]; *(ushort4*)(yr + 768 + 4 * L)  = yhi[1];
        *(ushort4*)(yr + 1024 + 4 * L) = ylr[0]; *(ushort4*)(yr + 1280 + 4 * L) = ylr[1];
        *(ushort4*)(yr + 1536 + 4 * L) = yli[0]; *(ushort4*)(yr + 1792 + 4 * L) = yli[1];
    }
#pragma unroll
    for (int off = 32; off; off >>= 1) {
        dd += __shfl_xor(dd, off, 64);
        nn += __shfl_xor(nn, off, 64);
    }
    if (L == 0) { red[rt] = dd; red[4 + rt] = nn; }
    __syncthreads();
    if (t == 0)
        *(float2*)(part + 2 * blockIdx.x) =
            make_float2(red[0] + red[1] + red[2] + red[3],
                        red[4] + red[5] + red[6] + red[7]);
}

// ---------------- convergence flag: reduce all NSLOT partials ----------------
__global__ __launch_bounds__(256) void k_flag(const float* __restrict__ part, int* __restrict__ active) {
    __shared__ float red[8];
    const int t = threadIdx.x, rt = t >> 6, L = t & 63;
    float dd = 0.f, nn = 0.f;
    for (int i = t; i < NSLOT; i += 256) {
        const float2 p = *(const float2*)(part + 2 * i);
        dd += p.x; nn += p.y;
    }
#pragma unroll
    for (int off = 32; off; off >>= 1) {
        dd += __shfl_xor(dd, off, 64);
        nn += __shfl_xor(nn, off, 64);
    }
    if (L == 0) { red[rt] = dd; red[4 + rt] = nn; }
    __syncthreads();
    if (t == 0) {
        const float d = red[0] + red[1] + red[2] + red[3];
        const float n = red[4] + red[5] + red[6] + red[7];
        const float diff = sqrtf(d) / (sqrtf(n) + 1e-8f);
        const int a = *active;
        *active = (a && (diff >= 1e-3f)) ? 1 : 0;
    }
}

// ---------------- mean over P ----------------
__global__ __launch_bounds__(256) void k_pool(const float* __restrict__ Sr, const float* __restrict__ Si,
        float* __restrict__ Pr, float* __restrict__ Pi) {
    const int gid = blockIdx.x * 256 + threadIdx.x;
    const int b = gid >> 9, d = gid & 511;
    const size_t base = (size_t)b * PP * DD + d;
    float sr = 0.f, si = 0.f;
    for (int p = 0; p < PP; p++) {
        sr += Sr[base + (size_t)p * DD];
        si += Si[base + (size_t)p * DD];
    }
    Pr[gid] = sr * (1.0f / 256.0f);
    Pi[gid] = si * (1.0f / 256.0f);
}

// ---------------- logits ----------------
__global__ __launch_bounds__(64) void k_logits(const float* __restrict__ Pr, const float* __restrict__ Pi,
        const float* __restrict__ Wr, const float* __restrict__ br,
        const float* __restrict__ Wi, const float* __restrict__ bi,
        float* __restrict__ out) {
    const int b = blockIdx.x;
    const int lane = threadIdx.x;
    for (int c = 0; c < CC; c++) {
        float acc = 0.f;
#pragma unroll
        for (int k = 0; k < 8; k++) {
            const int d = lane + 64 * k;
            acc += Pr[b * DD + d] * Wr[c * DD + d] + Pi[b * DD + d] * Wi[c * DD + d];
        }
#pragma unroll
        for (int off = 32; off; off >>= 1) acc += __shfl_xor(acc, off, 64);
        if (lane == 0) out[b * CC + c] = acc + br[c] + bi[c];
    }
}

extern "C" void kernel_launch(void* const* d_in, const int* in_sizes, int n_in,
                              void* d_out, int out_size, void* d_ws, size_t ws_size,
                              hipStream_t stream) {
    const float* x     = (const float*)d_in[0];
    const float* Wp    = (const float*)d_in[1];
    const float* bp    = (const float*)d_in[2];
    const float* q_rot = (const float*)d_in[3];
    const float* k_rot = (const float*)d_in[4];
    const float* v_rot = (const float*)d_in[5];
    const float* ffr   = (const float*)d_in[6];
    const float* ffi   = (const float*)d_in[7];
    const float* Wr    = (const float*)d_in[8];
    const float* br    = (const float*)d_in[9];
    const float* Wi    = (const float*)d_in[10];
    const float* bi    = (const float*)d_in[11];
    float* out = (float*)d_out;

    float* ws = (float*)d_ws;
    const size_t plane = (size_t)MTOT * DD;      // 16,777,216 floats
    const size_t sline = (size_t)PP * DD;

    float* freq = ws;                  // 512
    float* cd   = freq + DD;
    float* sd   = cd + DD;
    float* cv   = sd + DD;
    float* sv   = cv + DD;
    int*   active = (int*)(sv + DD);   // 1
    float* Pr = ws + 4096;             // 65536
    float* Pi = Pr + (size_t)BB * DD;  // 65536
    float* part = Pi + (size_t)BB * DD;        // 2*NSLOT = 16384 floats
    float* Sr = part + 2 * NSLOT;              // fp32 state (128 MiB)
    float* Si = Sr + plane;
    unsigned short* Bt2 = (unsigned short*)(Si + plane);   // 1024x2048 bf16 (4 MB)
    float* Tc = (float*)(Bt2 + (size_t)NK * KB2);          // 256x512 f32 (512 KB), inside 6MB hole
    float* Ts = Tc + (size_t)PP * DD;                      // 256x512 f32 (512 KB)
    float* chunkbase = Si + plane + (size_t)NK * 3072 / 2; // 6MB hole reserved (Bt2+Tc+Ts fit)

    const size_t fixed_f = (4096 + 2 * (size_t)BB * DD + 2 * NSLOT) + 2 * plane + (size_t)NK * 3072 / 2;
    // per-sample: X/U overlay (1 MB) + Y/A2 overlay (1 MB) + Asp (256 KB) = 2.25 MB
    const size_t perC_f = (size_t)PP * NK * 2 + (size_t)PP * 256;   // 589824 floats

    int C = BB;
    while (C > 1 && (fixed_f + (size_t)C * perC_f) * 4ull > ws_size) C >>= 1;
    const int fullXY = (C == BB);      // X/Y persist across iterations -> norm packs them

    float* U = chunkbase;                                       // C x 256 x 1024 fp32
    unsigned short* X  = (unsigned short*)chunkbase;            // overlay: X dead before ff writes U
    float* Yf = chunkbase + (size_t)C * PP * NK;
    unsigned short* Y  = (unsigned short*)Yf;                   // C x 256 x 2048 bf16
    unsigned short* A2 = Y;                                     // overlay: Y dead after k_score_sm
    unsigned short* Asp = (unsigned short*)(Yf + (size_t)C * PP * NK);  // C x 256 x 512 bf16

    k_setup<<<1, 512, 0, stream>>>(q_rot, k_rot, v_rot, freq, cd, sd, cv, sv, active);
    k_tab<<<PP, 256, 0, stream>>>(freq, Tc, Ts);
    k_prep2<<<NK, 256, 0, stream>>>(ffr, ffi, Bt2);
    k_init<<<dim3(DD / 64, MTOT / 64), 256, 0, stream>>>(x, Wp, bp, Tc, Ts, Sr, Si);

    for (int it = 0; it < 4; ++it) {
        for (int c0 = 0; c0 < BB; c0 += C) {
            float* Sr_c = Sr + (size_t)c0 * sline;
            float* Si_c = Si + (size_t)c0 * sline;
            float* part_c = part + (size_t)c0 * (PP / 4) * 2;
            if (!fullXY || it == 0)
                k_xy<<<C * PP, 256, 0, stream>>>(Sr_c, Si_c, cd, sd, X, Y, active);
            k_score_sm<<<C * 4, 256, 0, stream>>>(X, Y, Asp, active);
            k_attnout_mfma<<<dim3(C * 2, 8), 256, 0, stream>>>(Asp, X, Sr_c, Si_c, cv, sv, A2, active);
            k_ff_mfma2<<<dim3(C * 2, NK / 128), 256, 0, stream>>>(A2, Bt2, U, active);
            k_norm<<<C * (PP / 4), 256, 0, stream>>>(U, Sr_c, Si_c, part_c, X, Y, cd, sd, fullXY, active);
        }
        k_flag<<<1, 256, 0, stream>>>(part, active);
    }

    k_pool<<<BB * DD / 256, 256, 0, stream>>>(Sr, Si, Pr, Pi);
    k_logits<<<BB, 64, 0, stream>>>(Pr, Pi, Wr, br, Wi, bi, out);
}